// Round 3
// baseline (3195.288 us; speedup 1.0000x reference)
//
#include <hip/hip_runtime.h>
#include <hip/hip_bf16.h>

// Problem constants (RWKV-7 Tmix: B=2, T=1024, C=2048, H=32, N=64)
#define BB 2
#define TT 1024
#define CC 2048
#define HH 32
#define BT 2048          // BB*TT tokens
#define GN_EPS 6.4e-4f   // 1e-5 * 8^2

typedef __attribute__((ext_vector_type(8))) __bf16 bf16x8;
typedef __attribute__((ext_vector_type(4))) float f32x4;

__device__ __forceinline__ float sigf(float x) { return 1.0f / (1.0f + expf(-x)); }

__device__ __forceinline__ void split_bf16(float x, __hip_bfloat16& hi, __hip_bfloat16& lo) {
  __hip_bfloat16 h = __float2bfloat16(x);
  hi = h;
  lo = __float2bfloat16(x - __bfloat162float(h));
}

// ---------------------------------------------------------------------------
// K1: token shift + six lerped projections.
// r/k/v get hi+lo split (feed the scan -> need ~fp32); w/a/g plain bf16.
// ---------------------------------------------------------------------------
__global__ __launch_bounds__(256) void k_prepx(
    const float* __restrict__ hid, const float* __restrict__ shift,
    const float* __restrict__ xrc, const float* __restrict__ xwc,
    const float* __restrict__ xkc, const float* __restrict__ xvc,
    const float* __restrict__ xac, const float* __restrict__ xgc,
    __hip_bfloat16* __restrict__ xrh, __hip_bfloat16* __restrict__ xrl,
    __hip_bfloat16* __restrict__ xw,
    __hip_bfloat16* __restrict__ xkh, __hip_bfloat16* __restrict__ xkl,
    __hip_bfloat16* __restrict__ xvh, __hip_bfloat16* __restrict__ xvl,
    __hip_bfloat16* __restrict__ xa, __hip_bfloat16* __restrict__ xg) {
  int idx = blockIdx.x * 256 + threadIdx.x;   // < BT*CC
  int c  = idx & (CC - 1);
  int bt = idx >> 11;
  int t  = bt & (TT - 1);
  int b  = bt >> 10;
  float hcur  = hid[idx];
  float hprev = (t == 0) ? shift[b * CC + c] : hid[idx - CC];
  float xx = hprev - hcur;
  split_bf16(fmaf(xx, xrc[c], hcur), xrh[idx], xrl[idx]);
  split_bf16(fmaf(xx, xkc[c], hcur), xkh[idx], xkl[idx]);
  split_bf16(fmaf(xx, xvc[c], hcur), xvh[idx], xvl[idx]);
  xw[idx] = __float2bfloat16(fmaf(xx, xwc[c], hcur));
  xa[idx] = __float2bfloat16(fmaf(xx, xac[c], hcur));
  xg[idx] = __float2bfloat16(fmaf(xx, xgc[c], hcur));
}

// ---------------------------------------------------------------------------
// K2: f32 -> hi+lo bf16 split (for Wr/Wk/Wv/Wo)
// ---------------------------------------------------------------------------
__global__ __launch_bounds__(256) void k_cvt2(const float* __restrict__ in,
                                              __hip_bfloat16* __restrict__ oh,
                                              __hip_bfloat16* __restrict__ ol) {
  int i = blockIdx.x * 256 + threadIdx.x;
  split_bf16(in[i], oh[i], ol[i]);
}

// ---------------------------------------------------------------------------
// K3: transpose-convert small LoRA "up" weights: in [2048][N0] f32 ->
//     out [NP][2048] bf16 (rows >= N0 zero-padded).
// ---------------------------------------------------------------------------
__global__ __launch_bounds__(256) void k_tr(const float* __restrict__ in,
                                            __hip_bfloat16* __restrict__ out,
                                            int N0) {
  int i = blockIdx.x * 256 + threadIdx.x;   // over NP*2048, grid exact
  int n = i >> 11;
  int k = i & 2047;
  float v = (n < N0) ? in[k * N0 + n] : 0.0f;
  out[i] = __float2bfloat16(v);
}

// ---------------------------------------------------------------------------
// K4: plain bf16 MFMA GEMM, C[M,N] f32 = A[M,K] @ B[N,K]^T
// block 256 thr (4 waves); block tile 128(M) x 64(N); wave tile 32x64.
// ---------------------------------------------------------------------------
__global__ __launch_bounds__(256) void k_gemm_bt(
    const __hip_bfloat16* __restrict__ A, const __hip_bfloat16* __restrict__ Bm,
    float* __restrict__ Cm, int M, int Nn, int K) {
  int tid  = threadIdx.x;
  int lane = tid & 63;
  int wv   = tid >> 6;
  int l15  = lane & 15;
  int quad = lane >> 4;
  int m0 = blockIdx.x * 128 + wv * 32;
  int n0 = blockIdx.y * 64;
  const __hip_bfloat16* ap0 = A + (m0 + l15) * K + quad * 8;
  const __hip_bfloat16* ap1 = ap0 + 16 * K;
  const __hip_bfloat16* bp  = Bm + (n0 + l15) * K + quad * 8;
  f32x4 z = {0.f, 0.f, 0.f, 0.f};
  f32x4 c00 = z, c01 = z, c02 = z, c03 = z;
  f32x4 c10 = z, c11 = z, c12 = z, c13 = z;
  for (int k0 = 0; k0 < K; k0 += 32) {
    bf16x8 a0v = *(const bf16x8*)(ap0 + k0);
    bf16x8 a1v = *(const bf16x8*)(ap1 + k0);
    bf16x8 b0v = *(const bf16x8*)(bp + k0);
    bf16x8 b1v = *(const bf16x8*)(bp + 16 * K + k0);
    bf16x8 b2v = *(const bf16x8*)(bp + 32 * K + k0);
    bf16x8 b3v = *(const bf16x8*)(bp + 48 * K + k0);
    c00 = __builtin_amdgcn_mfma_f32_16x16x32_bf16(a0v, b0v, c00, 0, 0, 0);
    c01 = __builtin_amdgcn_mfma_f32_16x16x32_bf16(a0v, b1v, c01, 0, 0, 0);
    c02 = __builtin_amdgcn_mfma_f32_16x16x32_bf16(a0v, b2v, c02, 0, 0, 0);
    c03 = __builtin_amdgcn_mfma_f32_16x16x32_bf16(a0v, b3v, c03, 0, 0, 0);
    c10 = __builtin_amdgcn_mfma_f32_16x16x32_bf16(a1v, b0v, c10, 0, 0, 0);
    c11 = __builtin_amdgcn_mfma_f32_16x16x32_bf16(a1v, b1v, c11, 0, 0, 0);
    c12 = __builtin_amdgcn_mfma_f32_16x16x32_bf16(a1v, b2v, c12, 0, 0, 0);
    c13 = __builtin_amdgcn_mfma_f32_16x16x32_bf16(a1v, b3v, c13, 0, 0, 0);
  }
  int colb = n0 + l15;
  int row0 = m0 + quad * 4;
#pragma unroll
  for (int r = 0; r < 4; ++r) {
    Cm[(row0 + r) * Nn + colb +  0] = c00[r];
    Cm[(row0 + r) * Nn + colb + 16] = c01[r];
    Cm[(row0 + r) * Nn + colb + 32] = c02[r];
    Cm[(row0 + r) * Nn + colb + 48] = c03[r];
    Cm[(row0 + 16 + r) * Nn + colb +  0] = c10[r];
    Cm[(row0 + 16 + r) * Nn + colb + 16] = c11[r];
    Cm[(row0 + 16 + r) * Nn + colb + 32] = c12[r];
    Cm[(row0 + 16 + r) * Nn + colb + 48] = c13[r];
  }
}

// ---------------------------------------------------------------------------
// K4b: split-precision GEMM: C = (Ah+Al)@(Bh+Bl)^T ~= Ah Bh + Ah Bl + Al Bh.
// Residual ~2^-17 relative -> effectively fp32.
// ---------------------------------------------------------------------------
__global__ __launch_bounds__(256) void k_gemm_bt3(
    const __hip_bfloat16* __restrict__ Ah, const __hip_bfloat16* __restrict__ Al,
    const __hip_bfloat16* __restrict__ Bh, const __hip_bfloat16* __restrict__ Bl,
    float* __restrict__ Cm, int M, int Nn, int K) {
  int tid  = threadIdx.x;
  int lane = tid & 63;
  int wv   = tid >> 6;
  int l15  = lane & 15;
  int quad = lane >> 4;
  int m0 = blockIdx.x * 128 + wv * 32;
  int n0 = blockIdx.y * 64;
  size_t aoff0 = (size_t)(m0 + l15) * K + quad * 8;
  size_t aoff1 = aoff0 + (size_t)16 * K;
  size_t boff  = (size_t)(n0 + l15) * K + quad * 8;
  f32x4 z = {0.f, 0.f, 0.f, 0.f};
  f32x4 c00 = z, c01 = z, c02 = z, c03 = z;
  f32x4 c10 = z, c11 = z, c12 = z, c13 = z;
  for (int k0 = 0; k0 < K; k0 += 32) {
    bf16x8 a0h = *(const bf16x8*)(Ah + aoff0 + k0);
    bf16x8 a1h = *(const bf16x8*)(Ah + aoff1 + k0);
    bf16x8 a0l = *(const bf16x8*)(Al + aoff0 + k0);
    bf16x8 a1l = *(const bf16x8*)(Al + aoff1 + k0);
    bf16x8 bh0 = *(const bf16x8*)(Bh + boff + k0);
    bf16x8 bh1 = *(const bf16x8*)(Bh + boff + (size_t)16 * K + k0);
    bf16x8 bh2 = *(const bf16x8*)(Bh + boff + (size_t)32 * K + k0);
    bf16x8 bh3 = *(const bf16x8*)(Bh + boff + (size_t)48 * K + k0);
    bf16x8 bl0 = *(const bf16x8*)(Bl + boff + k0);
    bf16x8 bl1 = *(const bf16x8*)(Bl + boff + (size_t)16 * K + k0);
    bf16x8 bl2 = *(const bf16x8*)(Bl + boff + (size_t)32 * K + k0);
    bf16x8 bl3 = *(const bf16x8*)(Bl + boff + (size_t)48 * K + k0);
    c00 = __builtin_amdgcn_mfma_f32_16x16x32_bf16(a0h, bh0, c00, 0, 0, 0);
    c01 = __builtin_amdgcn_mfma_f32_16x16x32_bf16(a0h, bh1, c01, 0, 0, 0);
    c02 = __builtin_amdgcn_mfma_f32_16x16x32_bf16(a0h, bh2, c02, 0, 0, 0);
    c03 = __builtin_amdgcn_mfma_f32_16x16x32_bf16(a0h, bh3, c03, 0, 0, 0);
    c10 = __builtin_amdgcn_mfma_f32_16x16x32_bf16(a1h, bh0, c10, 0, 0, 0);
    c11 = __builtin_amdgcn_mfma_f32_16x16x32_bf16(a1h, bh1, c11, 0, 0, 0);
    c12 = __builtin_amdgcn_mfma_f32_16x16x32_bf16(a1h, bh2, c12, 0, 0, 0);
    c13 = __builtin_amdgcn_mfma_f32_16x16x32_bf16(a1h, bh3, c13, 0, 0, 0);
    c00 = __builtin_amdgcn_mfma_f32_16x16x32_bf16(a0h, bl0, c00, 0, 0, 0);
    c01 = __builtin_amdgcn_mfma_f32_16x16x32_bf16(a0h, bl1, c01, 0, 0, 0);
    c02 = __builtin_amdgcn_mfma_f32_16x16x32_bf16(a0h, bl2, c02, 0, 0, 0);
    c03 = __builtin_amdgcn_mfma_f32_16x16x32_bf16(a0h, bl3, c03, 0, 0, 0);
    c10 = __builtin_amdgcn_mfma_f32_16x16x32_bf16(a1h, bl0, c10, 0, 0, 0);
    c11 = __builtin_amdgcn_mfma_f32_16x16x32_bf16(a1h, bl1, c11, 0, 0, 0);
    c12 = __builtin_amdgcn_mfma_f32_16x16x32_bf16(a1h, bl2, c12, 0, 0, 0);
    c13 = __builtin_amdgcn_mfma_f32_16x16x32_bf16(a1h, bl3, c13, 0, 0, 0);
    c00 = __builtin_amdgcn_mfma_f32_16x16x32_bf16(a0l, bh0, c00, 0, 0, 0);
    c01 = __builtin_amdgcn_mfma_f32_16x16x32_bf16(a0l, bh1, c01, 0, 0, 0);
    c02 = __builtin_amdgcn_mfma_f32_16x16x32_bf16(a0l, bh2, c02, 0, 0, 0);
    c03 = __builtin_amdgcn_mfma_f32_16x16x32_bf16(a0l, bh3, c03, 0, 0, 0);
    c10 = __builtin_amdgcn_mfma_f32_16x16x32_bf16(a1l, bh0, c10, 0, 0, 0);
    c11 = __builtin_amdgcn_mfma_f32_16x16x32_bf16(a1l, bh1, c11, 0, 0, 0);
    c12 = __builtin_amdgcn_mfma_f32_16x16x32_bf16(a1l, bh2, c12, 0, 0, 0);
    c13 = __builtin_amdgcn_mfma_f32_16x16x32_bf16(a1l, bh3, c13, 0, 0, 0);
  }
  int colb = n0 + l15;
  int row0 = m0 + quad * 4;
#pragma unroll
  for (int r = 0; r < 4; ++r) {
    Cm[(row0 + r) * Nn + colb +  0] = c00[r];
    Cm[(row0 + r) * Nn + colb + 16] = c01[r];
    Cm[(row0 + r) * Nn + colb + 32] = c02[r];
    Cm[(row0 + r) * Nn + colb + 48] = c03[r];
    Cm[(row0 + 16 + r) * Nn + colb +  0] = c10[r];
    Cm[(row0 + 16 + r) * Nn + colb + 16] = c11[r];
    Cm[(row0 + 16 + r) * Nn + colb + 32] = c12[r];
    Cm[(row0 + 16 + r) * Nn + colb + 48] = c13[r];
  }
}

// ---------------------------------------------------------------------------
// K5: activations on stage-1 LoRA outputs: tanh(h1w), sigmoid(h1g), in place
// ---------------------------------------------------------------------------
__global__ __launch_bounds__(256) void k_act(float* __restrict__ h1w,
                                             float* __restrict__ h1g) {
  int i = blockIdx.x * 256 + threadIdx.x;   // grid covers BT*128
  if (i < BT * 64)  h1w[i] = tanhf(h1w[i]);
  if (i < BT * 128) h1g[i] = sigf(h1g[i]);
}

// ---------------------------------------------------------------------------
// K6: fused stage-2 LoRA dots (f32) + gates + kk-normalize -> scan inputs.
// Block: 256 c-channels x 8 tokens. hs LDS: [288 d][8 tt]. Wave == head.
// kbuf is read (raw k) then overwritten with k_final; vbuf likewise -> v_mix.
// ---------------------------------------------------------------------------
__global__ __launch_bounds__(256) void k_prep2(
    const float* __restrict__ h1w, const float* __restrict__ h1a,
    const float* __restrict__ h1v, const float* __restrict__ h1g,
    const float* __restrict__ w2, const float* __restrict__ a2,
    const float* __restrict__ v2, const float* __restrict__ g2,
    const float* __restrict__ w0, const float* __restrict__ a0,
    const float* __restrict__ v0, const float* __restrict__ kkc,
    const float* __restrict__ kac, float* __restrict__ kbuf,
    float* __restrict__ vbuf, const float* __restrict__ vfirst,
    float* __restrict__ dec, float* __restrict__ aw,
    float* __restrict__ bw, float* __restrict__ gval) {
  __shared__ float hs[288][8];   // w:0-63  a:64-127  v:128-159  g:160-287
  int tid = threadIdx.x;
  int c   = blockIdx.x * 256 + tid;
  int t0  = blockIdx.y * 8;
  for (int e = tid; e < 64 * 8;  e += 256) { int d = e >> 3, q = e & 7; hs[d][q]       = h1w[(t0 + q) * 64  + d]; }
  for (int e = tid; e < 64 * 8;  e += 256) { int d = e >> 3, q = e & 7; hs[64 + d][q]  = h1a[(t0 + q) * 64  + d]; }
  for (int e = tid; e < 32 * 8;  e += 256) { int d = e >> 3, q = e & 7; hs[128 + d][q] = h1v[(t0 + q) * 64  + d]; }
  for (int e = tid; e < 128 * 8; e += 256) { int d = e >> 3, q = e & 7; hs[160 + d][q] = h1g[(t0 + q) * 128 + d]; }
  __syncthreads();
  float wacc[8], aacc[8], vacc[8], gacc[8];
#pragma unroll
  for (int q = 0; q < 8; ++q) { wacc[q] = 0.f; aacc[q] = 0.f; vacc[q] = 0.f; gacc[q] = 0.f; }
  for (int d = 0; d < 64; ++d) {
    float wt = w2[d * CC + c];
    float4 h0 = *(const float4*)&hs[d][0];
    float4 h1 = *(const float4*)&hs[d][4];
    wacc[0] = fmaf(h0.x, wt, wacc[0]); wacc[1] = fmaf(h0.y, wt, wacc[1]);
    wacc[2] = fmaf(h0.z, wt, wacc[2]); wacc[3] = fmaf(h0.w, wt, wacc[3]);
    wacc[4] = fmaf(h1.x, wt, wacc[4]); wacc[5] = fmaf(h1.y, wt, wacc[5]);
    wacc[6] = fmaf(h1.z, wt, wacc[6]); wacc[7] = fmaf(h1.w, wt, wacc[7]);
  }
  for (int d = 0; d < 64; ++d) {
    float at = a2[d * CC + c];
    float4 h0 = *(const float4*)&hs[64 + d][0];
    float4 h1 = *(const float4*)&hs[64 + d][4];
    aacc[0] = fmaf(h0.x, at, aacc[0]); aacc[1] = fmaf(h0.y, at, aacc[1]);
    aacc[2] = fmaf(h0.z, at, aacc[2]); aacc[3] = fmaf(h0.w, at, aacc[3]);
    aacc[4] = fmaf(h1.x, at, aacc[4]); aacc[5] = fmaf(h1.y, at, aacc[5]);
    aacc[6] = fmaf(h1.z, at, aacc[6]); aacc[7] = fmaf(h1.w, at, aacc[7]);
  }
  for (int d = 0; d < 32; ++d) {
    float vt = v2[d * CC + c];
    float4 h0 = *(const float4*)&hs[128 + d][0];
    float4 h1 = *(const float4*)&hs[128 + d][4];
    vacc[0] = fmaf(h0.x, vt, vacc[0]); vacc[1] = fmaf(h0.y, vt, vacc[1]);
    vacc[2] = fmaf(h0.z, vt, vacc[2]); vacc[3] = fmaf(h0.w, vt, vacc[3]);
    vacc[4] = fmaf(h1.x, vt, vacc[4]); vacc[5] = fmaf(h1.y, vt, vacc[5]);
    vacc[6] = fmaf(h1.z, vt, vacc[6]); vacc[7] = fmaf(h1.w, vt, vacc[7]);
  }
  for (int d = 0; d < 128; ++d) {
    float gt = g2[d * CC + c];
    float4 h0 = *(const float4*)&hs[160 + d][0];
    float4 h1 = *(const float4*)&hs[160 + d][4];
    gacc[0] = fmaf(h0.x, gt, gacc[0]); gacc[1] = fmaf(h0.y, gt, gacc[1]);
    gacc[2] = fmaf(h0.z, gt, gacc[2]); gacc[3] = fmaf(h0.w, gt, gacc[3]);
    gacc[4] = fmaf(h1.x, gt, gacc[4]); gacc[5] = fmaf(h1.y, gt, gacc[5]);
    gacc[6] = fmaf(h1.z, gt, gacc[6]); gacc[7] = fmaf(h1.w, gt, gacc[7]);
  }
  float w0v = w0[c], a0v = a0[c], v0v = v0[c], kkv = kkc[c], kav = kac[c];
  for (int q = 0; q < 8; ++q) {
    int idx = (t0 + q) * CC + c;
    float kv = kbuf[idx], vv = vbuf[idx], vf = vfirst[idx];
    // decay = exp(-softplus(-wpre) - 0.5) = sigmoid(wpre) * exp(-0.5)
    float d_ = 0.60653065971f * sigf(w0v + wacc[q]);
    float as = sigf(a0v + aacc[q]);
    float vs = sigf(v0v + vacc[q]);
    float vm = vv + (vf - vv) * vs;
    float kfv = kv * (1.0f + kav * (as - 1.0f));
    float kku = kv * kkv;
    float s = kku * kku;     // per-head L2 over 64 lanes (wave == head)
    s += __shfl_xor(s, 1);  s += __shfl_xor(s, 2);  s += __shfl_xor(s, 4);
    s += __shfl_xor(s, 8);  s += __shfl_xor(s, 16); s += __shfl_xor(s, 32);
    float nrm = fmaxf(sqrtf(s), 1e-12f);
    float kkn = kku / nrm;
    dec[idx] = d_;
    aw[idx]  = -kkn; bw[idx] = kkn * as;
    kbuf[idx] = kfv; vbuf[idx] = vm; gval[idx] = gacc[q];
  }
}

// ---------------------------------------------------------------------------
// K7: WKV7 scan + fused GroupNorm + bonus + g-gate. 1 wave per (b,h).
// Emits hi/lo bf16 (split) so the Wo GEMM can run split-precision.
// ---------------------------------------------------------------------------
__global__ __launch_bounds__(64) void k_scan(
    const float* __restrict__ rbuf, const float* __restrict__ kf,
    const float* __restrict__ dec, const float* __restrict__ aw,
    const float* __restrict__ bw, const float* __restrict__ vbuf,
    const float* __restrict__ gval, const float* __restrict__ st0,
    const float* __restrict__ rk, const float* __restrict__ gnw,
    const float* __restrict__ gnb,
    __hip_bfloat16* __restrict__ xoh, __hip_bfloat16* __restrict__ xol) {
  int bh   = blockIdx.x;          // b*32 + h
  int b    = bh >> 5;
  int lane = threadIdx.x;         // row i == v-dim within head
  int c    = (bh & 31) * 64 + lane;
  int base = b * TT * CC + c;
  float S[64];
  const float* sp = st0 + (bh * 64 + lane) * 64;
#pragma unroll
  for (int j = 0; j < 64; ++j) S[j] = sp[j];
  float rkc = rk[c], gnwc = gnw[c], gnbc = gnb[c];
  __shared__ float4 p1[64];      // (d, bw, kf, r)
  __shared__ float4 aw4[16];     // a_wkv packed
  float rv = rbuf[base], kfv = kf[base], dv = dec[base], awv = aw[base];
  float bwv = bw[base], vv = vbuf[base], gv = gval[base];
  for (int t = 0; t < TT; ++t) {
    p1[lane] = make_float4(dv, bwv, kfv, rv);
    ((float*)aw4)[lane] = awv;
    float r_c = rv, kf_c = kfv, v_i = vv, g_c = gv;
    __syncthreads();
    if (t + 1 < TT) {            // prefetch next token (hides HBM latency)
      int nb = base + (t + 1) * CC;
      rv = rbuf[nb]; kfv = kf[nb]; dv = dec[nb]; awv = aw[nb];
      bwv = bw[nb]; vv = vbuf[nb]; gv = gval[nb];
    }
    float sa0 = 0.f, sa1 = 0.f, sa2 = 0.f, sa3 = 0.f;
#pragma unroll
    for (int j4 = 0; j4 < 16; ++j4) {
      float4 a4 = aw4[j4];
      sa0 = fmaf(a4.x, S[4 * j4 + 0], sa0);
      sa1 = fmaf(a4.y, S[4 * j4 + 1], sa1);
      sa2 = fmaf(a4.z, S[4 * j4 + 2], sa2);
      sa3 = fmaf(a4.w, S[4 * j4 + 3], sa3);
    }
    float sa = (sa0 + sa1) + (sa2 + sa3);
    float yv[4] = {0.f, 0.f, 0.f, 0.f};
#pragma unroll
    for (int j = 0; j < 64; ++j) {
      float4 p = p1[j];
      float s = fmaf(S[j], p.x, fmaf(sa, p.y, v_i * p.z));
      S[j] = s;
      yv[j & 3] = fmaf(s, p.w, yv[j & 3]);
    }
    float y = (yv[0] + yv[1]) + (yv[2] + yv[3]);
    float s1 = y, s2 = y * y, s3 = r_c * kf_c * rkc;
#pragma unroll
    for (int off = 1; off < 64; off <<= 1) {
      s1 += __shfl_xor(s1, off);
      s2 += __shfl_xor(s2, off);
      s3 += __shfl_xor(s3, off);
    }
    float mean = s1 * (1.0f / 64.0f);
    float var  = s2 * (1.0f / 64.0f) - mean * mean;
    float inv  = rsqrtf(var + GN_EPS);
    float x = fmaf((y - mean) * inv, gnwc, gnbc) + s3 * v_i;
    split_bf16(x * g_c, xoh[base + t * CC], xol[base + t * CC]);
    __syncthreads();
  }
}

// ---------------------------------------------------------------------------
extern "C" void kernel_launch(void* const* d_in, const int* in_sizes, int n_in,
                              void* d_out, int out_size, void* d_ws, size_t ws_size,
                              hipStream_t stream) {
  (void)in_sizes; (void)n_in; (void)out_size; (void)ws_size;
  const float* hid    = (const float*)d_in[0];
  const float* shift  = (const float*)d_in[1];
  const float* st0    = (const float*)d_in[2];
  const float* vfirst = (const float*)d_in[3];
  const float* xrc = (const float*)d_in[4];
  const float* xwc = (const float*)d_in[5];
  const float* xkc = (const float*)d_in[6];
  const float* xvc = (const float*)d_in[7];
  const float* xac = (const float*)d_in[8];
  const float* xgc = (const float*)d_in[9];
  const float* w0  = (const float*)d_in[10];
  const float* w1  = (const float*)d_in[11];
  const float* w2  = (const float*)d_in[12];
  const float* a0  = (const float*)d_in[13];
  const float* a1  = (const float*)d_in[14];
  const float* a2  = (const float*)d_in[15];
  const float* v0  = (const float*)d_in[16];
  const float* v1  = (const float*)d_in[17];
  const float* v2  = (const float*)d_in[18];
  const float* g1  = (const float*)d_in[19];
  const float* g2  = (const float*)d_in[20];
  const float* kkc = (const float*)d_in[21];
  const float* kac = (const float*)d_in[22];
  const float* rk  = (const float*)d_in[23];
  const float* Wr  = (const float*)d_in[24];
  const float* Wk  = (const float*)d_in[25];
  const float* Wv  = (const float*)d_in[26];
  const float* Wo  = (const float*)d_in[27];
  const float* gnw = (const float*)d_in[28];
  const float* gnb = (const float*)d_in[29];
  float* out = (float*)d_out;

  char* p = (char*)d_ws;
  auto alloc = [&](size_t n) { char* q = p; p += (n + 255) & ~(size_t)255; return q; };
  const size_t EL = (size_t)BT * CC;

  // --- alias pool (96 MiB): xrh..xvl + Wrh,Wrl are all dead by k_prep2 time;
  //     db/awb/bwb/gvb (64 MiB) overlay them. Allocation order matters!
  char* pool = p;
  __hip_bfloat16* xrh = (__hip_bfloat16*)alloc(EL * 2);
  __hip_bfloat16* xrl = (__hip_bfloat16*)alloc(EL * 2);
  __hip_bfloat16* xkh = (__hip_bfloat16*)alloc(EL * 2);
  __hip_bfloat16* xkl = (__hip_bfloat16*)alloc(EL * 2);
  __hip_bfloat16* xvh = (__hip_bfloat16*)alloc(EL * 2);
  __hip_bfloat16* xvl = (__hip_bfloat16*)alloc(EL * 2);
  __hip_bfloat16* Wrh = (__hip_bfloat16*)alloc((size_t)CC * CC * 2);
  __hip_bfloat16* Wrl = (__hip_bfloat16*)alloc((size_t)CC * CC * 2);
  float* db  = (float*)pool;           // overlays xrh+xrl
  float* awb = db + EL;                // overlays xkh+xkl
  float* bwb = db + 2 * EL;            // overlays xvh+xvl
  float* gvb = db + 3 * EL;            // overlays Wrh+Wrl

  __hip_bfloat16* Wkh = (__hip_bfloat16*)alloc((size_t)CC * CC * 2);
  __hip_bfloat16* Wkl = (__hip_bfloat16*)alloc((size_t)CC * CC * 2);
  __hip_bfloat16* Wvh = (__hip_bfloat16*)alloc((size_t)CC * CC * 2);
  __hip_bfloat16* Wvl = (__hip_bfloat16*)alloc((size_t)CC * CC * 2);
  __hip_bfloat16* Woh = (__hip_bfloat16*)alloc((size_t)CC * CC * 2);
  __hip_bfloat16* Wol = (__hip_bfloat16*)alloc((size_t)CC * CC * 2);
  __hip_bfloat16* xw  = (__hip_bfloat16*)alloc(EL * 2);
  __hip_bfloat16* xa  = (__hip_bfloat16*)alloc(EL * 2);
  __hip_bfloat16* xg  = (__hip_bfloat16*)alloc(EL * 2);
  __hip_bfloat16* w1t = (__hip_bfloat16*)alloc((size_t)64  * CC * 2);
  __hip_bfloat16* a1t = (__hip_bfloat16*)alloc((size_t)64  * CC * 2);
  __hip_bfloat16* v1t = (__hip_bfloat16*)alloc((size_t)64  * CC * 2);
  __hip_bfloat16* g1t = (__hip_bfloat16*)alloc((size_t)128 * CC * 2);
  float* rb  = (float*)alloc(EL * 4);
  float* kb  = (float*)alloc(EL * 4);  // raw k, then k_final in place
  float* vb  = (float*)alloc(EL * 4);  // raw v, then v_mix in place
  float* h1w = (float*)alloc((size_t)BT * 64  * 4);
  float* h1a = (float*)alloc((size_t)BT * 64  * 4);
  float* h1v = (float*)alloc((size_t)BT * 64  * 4);
  float* h1g = (float*)alloc((size_t)BT * 128 * 4);
  __hip_bfloat16* xoh = (__hip_bfloat16*)alloc(EL * 2);
  __hip_bfloat16* xol = (__hip_bfloat16*)alloc(EL * 2);
  // total ~204 MiB (fits: 220 MiB known-OK, 268 MiB crashed)

  k_prepx<<<16384, 256, 0, stream>>>(hid, shift, xrc, xwc, xkc, xvc, xac, xgc,
                                     xrh, xrl, xw, xkh, xkl, xvh, xvl, xa, xg);
  k_cvt2<<<16384, 256, 0, stream>>>(Wr, Wrh, Wrl);
  k_cvt2<<<16384, 256, 0, stream>>>(Wk, Wkh, Wkl);
  k_cvt2<<<16384, 256, 0, stream>>>(Wv, Wvh, Wvl);
  k_cvt2<<<16384, 256, 0, stream>>>(Wo, Woh, Wol);
  k_tr<<<512, 256, 0, stream>>>(w1, w1t, 64);
  k_tr<<<512, 256, 0, stream>>>(a1, a1t, 64);
  k_tr<<<512, 256, 0, stream>>>(v1, v1t, 32);   // pad rows 32..63 with zeros
  k_tr<<<1024, 256, 0, stream>>>(g1, g1t, 128);

  k_gemm_bt3<<<dim3(16, 32), 256, 0, stream>>>(xrh, xrl, Wrh, Wrl, rb, BT, CC, CC);
  k_gemm_bt3<<<dim3(16, 32), 256, 0, stream>>>(xkh, xkl, Wkh, Wkl, kb, BT, CC, CC);
  k_gemm_bt3<<<dim3(16, 32), 256, 0, stream>>>(xvh, xvl, Wvh, Wvl, vb, BT, CC, CC);
  k_gemm_bt<<<dim3(16, 1),  256, 0, stream>>>(xw,  w1t, h1w, BT, 64, CC);
  k_gemm_bt<<<dim3(16, 1),  256, 0, stream>>>(xa,  a1t, h1a, BT, 64, CC);
  k_gemm_bt<<<dim3(16, 1),  256, 0, stream>>>(xvh, v1t, h1v, BT, 64, CC);
  k_gemm_bt<<<dim3(16, 2),  256, 0, stream>>>(xg,  g1t, h1g, BT, 128, CC);

  k_act<<<1024, 256, 0, stream>>>(h1w, h1g);
  // from here on, xrh..xvl / Wrh,Wrl are dead -> db/awb/bwb/gvb overlay them
  k_prep2<<<dim3(8, 256), 256, 0, stream>>>(h1w, h1a, h1v, h1g, w2, a2, v2, g2,
                                            w0, a0, v0, kkc, kac, kb, vb, vfirst,
                                            db, awb, bwb, gvb);
  k_scan<<<64, 64, 0, stream>>>(rb, kb, db, awb, bwb, vb, gvb, st0, rk, gnw, gnb,
                                xoh, xol);
  k_gemm_bt3<<<dim3(16, 32), 256, 0, stream>>>(xoh, xol, Woh, Wol, out, BT, CC, CC);
}

// Round 5
// 2420.255 us; speedup vs baseline: 1.3202x; 1.3202x over previous
//
#include <hip/hip_runtime.h>
#include <hip/hip_bf16.h>

// Problem constants (RWKV-7 Tmix: B=2, T=1024, C=2048, H=32, N=64)
#define BB 2
#define TT 1024
#define CC 2048
#define HH 32
#define BT 2048          // BB*TT tokens
#define GN_EPS 6.4e-4f   // 1e-5 * 8^2

typedef __attribute__((ext_vector_type(8))) __bf16 bf16x8;
typedef __attribute__((ext_vector_type(4))) float f32x4;

__device__ __forceinline__ float sigf(float x) { return 1.0f / (1.0f + expf(-x)); }

__device__ __forceinline__ void split_bf16(float x, __hip_bfloat16& hi, __hip_bfloat16& lo) {
  __hip_bfloat16 h = __float2bfloat16(x);
  hi = h;
  lo = __float2bfloat16(x - __bfloat162float(h));
}

// ---------------------------------------------------------------------------
// K1: token shift + six lerped projections.
// r/k/v get hi+lo split (ALL scan inputs are error-critical: r passes
// multiplicatively through GN — round-4 lesson); w/a/g plain bf16.
// ---------------------------------------------------------------------------
__global__ __launch_bounds__(256) void k_prepx(
    const float* __restrict__ hid, const float* __restrict__ shift,
    const float* __restrict__ xrc, const float* __restrict__ xwc,
    const float* __restrict__ xkc, const float* __restrict__ xvc,
    const float* __restrict__ xac, const float* __restrict__ xgc,
    __hip_bfloat16* __restrict__ xrh, __hip_bfloat16* __restrict__ xrl,
    __hip_bfloat16* __restrict__ xw,
    __hip_bfloat16* __restrict__ xkh, __hip_bfloat16* __restrict__ xkl,
    __hip_bfloat16* __restrict__ xvh, __hip_bfloat16* __restrict__ xvl,
    __hip_bfloat16* __restrict__ xa, __hip_bfloat16* __restrict__ xg) {
  int idx = blockIdx.x * 256 + threadIdx.x;   // < BT*CC
  int c  = idx & (CC - 1);
  int bt = idx >> 11;
  int t  = bt & (TT - 1);
  int b  = bt >> 10;
  float hcur  = hid[idx];
  float hprev = (t == 0) ? shift[b * CC + c] : hid[idx - CC];
  float xx = hprev - hcur;
  split_bf16(fmaf(xx, xrc[c], hcur), xrh[idx], xrl[idx]);
  split_bf16(fmaf(xx, xkc[c], hcur), xkh[idx], xkl[idx]);
  split_bf16(fmaf(xx, xvc[c], hcur), xvh[idx], xvl[idx]);
  xw[idx] = __float2bfloat16(fmaf(xx, xwc[c], hcur));
  xa[idx] = __float2bfloat16(fmaf(xx, xac[c], hcur));
  xg[idx] = __float2bfloat16(fmaf(xx, xgc[c], hcur));
}

// ---------------------------------------------------------------------------
// K2: f32 -> hi+lo bf16 split (for Wr/Wk/Wv/Wo)
// ---------------------------------------------------------------------------
__global__ __launch_bounds__(256) void k_cvt2(const float* __restrict__ in,
                                              __hip_bfloat16* __restrict__ oh,
                                              __hip_bfloat16* __restrict__ ol) {
  int i = blockIdx.x * 256 + threadIdx.x;
  split_bf16(in[i], oh[i], ol[i]);
}

// ---------------------------------------------------------------------------
// K3: transpose-convert small LoRA "up" weights: in [2048][N0] f32 ->
//     out [NP][2048] bf16 (rows >= N0 zero-padded).
// ---------------------------------------------------------------------------
__global__ __launch_bounds__(256) void k_tr(const float* __restrict__ in,
                                            __hip_bfloat16* __restrict__ out,
                                            int N0) {
  int i = blockIdx.x * 256 + threadIdx.x;   // over NP*2048, grid exact
  int n = i >> 11;
  int k = i & 2047;
  float v = (n < N0) ? in[k * N0 + n] : 0.0f;
  out[i] = __float2bfloat16(v);
}

// ---------------------------------------------------------------------------
// K4: plain bf16 MFMA GEMM, C[M,N] f32 = A[M,K] @ B[N,K]^T
// (used only for LoRA stage-1: w/a/v1/g paths, error-damped through gates)
// ---------------------------------------------------------------------------
__global__ __launch_bounds__(256) void k_gemm_bt(
    const __hip_bfloat16* __restrict__ A, const __hip_bfloat16* __restrict__ Bm,
    float* __restrict__ Cm, int M, int Nn, int K) {
  int tid  = threadIdx.x;
  int lane = tid & 63;
  int wv   = tid >> 6;
  int l15  = lane & 15;
  int quad = lane >> 4;
  int m0 = blockIdx.x * 128 + wv * 32;
  int n0 = blockIdx.y * 64;
  const __hip_bfloat16* ap0 = A + (m0 + l15) * K + quad * 8;
  const __hip_bfloat16* ap1 = ap0 + 16 * K;
  const __hip_bfloat16* bp  = Bm + (n0 + l15) * K + quad * 8;
  f32x4 z = {0.f, 0.f, 0.f, 0.f};
  f32x4 c00 = z, c01 = z, c02 = z, c03 = z;
  f32x4 c10 = z, c11 = z, c12 = z, c13 = z;
  for (int k0 = 0; k0 < K; k0 += 32) {
    bf16x8 a0v = *(const bf16x8*)(ap0 + k0);
    bf16x8 a1v = *(const bf16x8*)(ap1 + k0);
    bf16x8 b0v = *(const bf16x8*)(bp + k0);
    bf16x8 b1v = *(const bf16x8*)(bp + 16 * K + k0);
    bf16x8 b2v = *(const bf16x8*)(bp + 32 * K + k0);
    bf16x8 b3v = *(const bf16x8*)(bp + 48 * K + k0);
    c00 = __builtin_amdgcn_mfma_f32_16x16x32_bf16(a0v, b0v, c00, 0, 0, 0);
    c01 = __builtin_amdgcn_mfma_f32_16x16x32_bf16(a0v, b1v, c01, 0, 0, 0);
    c02 = __builtin_amdgcn_mfma_f32_16x16x32_bf16(a0v, b2v, c02, 0, 0, 0);
    c03 = __builtin_amdgcn_mfma_f32_16x16x32_bf16(a0v, b3v, c03, 0, 0, 0);
    c10 = __builtin_amdgcn_mfma_f32_16x16x32_bf16(a1v, b0v, c10, 0, 0, 0);
    c11 = __builtin_amdgcn_mfma_f32_16x16x32_bf16(a1v, b1v, c11, 0, 0, 0);
    c12 = __builtin_amdgcn_mfma_f32_16x16x32_bf16(a1v, b2v, c12, 0, 0, 0);
    c13 = __builtin_amdgcn_mfma_f32_16x16x32_bf16(a1v, b3v, c13, 0, 0, 0);
  }
  int colb = n0 + l15;
  int row0 = m0 + quad * 4;
#pragma unroll
  for (int r = 0; r < 4; ++r) {
    Cm[(row0 + r) * Nn + colb +  0] = c00[r];
    Cm[(row0 + r) * Nn + colb + 16] = c01[r];
    Cm[(row0 + r) * Nn + colb + 32] = c02[r];
    Cm[(row0 + r) * Nn + colb + 48] = c03[r];
    Cm[(row0 + 16 + r) * Nn + colb +  0] = c10[r];
    Cm[(row0 + 16 + r) * Nn + colb + 16] = c11[r];
    Cm[(row0 + 16 + r) * Nn + colb + 32] = c12[r];
    Cm[(row0 + 16 + r) * Nn + colb + 48] = c13[r];
  }
}

// ---------------------------------------------------------------------------
// K4b: split-precision GEMM: C = (Ah+Al)@(Bh+Bl)^T ~= Ah Bh + Ah Bl + Al Bh.
// Used for ALL of r/k/v/out — every scan-coupled value needs ~fp32.
// ---------------------------------------------------------------------------
__global__ __launch_bounds__(256) void k_gemm_bt3(
    const __hip_bfloat16* __restrict__ Ah, const __hip_bfloat16* __restrict__ Al,
    const __hip_bfloat16* __restrict__ Bh, const __hip_bfloat16* __restrict__ Bl,
    float* __restrict__ Cm, int M, int Nn, int K) {
  int tid  = threadIdx.x;
  int lane = tid & 63;
  int wv   = tid >> 6;
  int l15  = lane & 15;
  int quad = lane >> 4;
  int m0 = blockIdx.x * 128 + wv * 32;
  int n0 = blockIdx.y * 64;
  size_t aoff0 = (size_t)(m0 + l15) * K + quad * 8;
  size_t aoff1 = aoff0 + (size_t)16 * K;
  size_t boff  = (size_t)(n0 + l15) * K + quad * 8;
  f32x4 z = {0.f, 0.f, 0.f, 0.f};
  f32x4 c00 = z, c01 = z, c02 = z, c03 = z;
  f32x4 c10 = z, c11 = z, c12 = z, c13 = z;
  for (int k0 = 0; k0 < K; k0 += 32) {
    bf16x8 a0h = *(const bf16x8*)(Ah + aoff0 + k0);
    bf16x8 a1h = *(const bf16x8*)(Ah + aoff1 + k0);
    bf16x8 a0l = *(const bf16x8*)(Al + aoff0 + k0);
    bf16x8 a1l = *(const bf16x8*)(Al + aoff1 + k0);
    bf16x8 bh0 = *(const bf16x8*)(Bh + boff + k0);
    bf16x8 bh1 = *(const bf16x8*)(Bh + boff + (size_t)16 * K + k0);
    bf16x8 bh2 = *(const bf16x8*)(Bh + boff + (size_t)32 * K + k0);
    bf16x8 bh3 = *(const bf16x8*)(Bh + boff + (size_t)48 * K + k0);
    bf16x8 bl0 = *(const bf16x8*)(Bl + boff + k0);
    bf16x8 bl1 = *(const bf16x8*)(Bl + boff + (size_t)16 * K + k0);
    bf16x8 bl2 = *(const bf16x8*)(Bl + boff + (size_t)32 * K + k0);
    bf16x8 bl3 = *(const bf16x8*)(Bl + boff + (size_t)48 * K + k0);
    c00 = __builtin_amdgcn_mfma_f32_16x16x32_bf16(a0h, bh0, c00, 0, 0, 0);
    c01 = __builtin_amdgcn_mfma_f32_16x16x32_bf16(a0h, bh1, c01, 0, 0, 0);
    c02 = __builtin_amdgcn_mfma_f32_16x16x32_bf16(a0h, bh2, c02, 0, 0, 0);
    c03 = __builtin_amdgcn_mfma_f32_16x16x32_bf16(a0h, bh3, c03, 0, 0, 0);
    c10 = __builtin_amdgcn_mfma_f32_16x16x32_bf16(a1h, bh0, c10, 0, 0, 0);
    c11 = __builtin_amdgcn_mfma_f32_16x16x32_bf16(a1h, bh1, c11, 0, 0, 0);
    c12 = __builtin_amdgcn_mfma_f32_16x16x32_bf16(a1h, bh2, c12, 0, 0, 0);
    c13 = __builtin_amdgcn_mfma_f32_16x16x32_bf16(a1h, bh3, c13, 0, 0, 0);
    c00 = __builtin_amdgcn_mfma_f32_16x16x32_bf16(a0h, bl0, c00, 0, 0, 0);
    c01 = __builtin_amdgcn_mfma_f32_16x16x32_bf16(a0h, bl1, c01, 0, 0, 0);
    c02 = __builtin_amdgcn_mfma_f32_16x16x32_bf16(a0h, bl2, c02, 0, 0, 0);
    c03 = __builtin_amdgcn_mfma_f32_16x16x32_bf16(a0h, bl3, c03, 0, 0, 0);
    c10 = __builtin_amdgcn_mfma_f32_16x16x32_bf16(a1h, bl0, c10, 0, 0, 0);
    c11 = __builtin_amdgcn_mfma_f32_16x16x32_bf16(a1h, bl1, c11, 0, 0, 0);
    c12 = __builtin_amdgcn_mfma_f32_16x16x32_bf16(a1h, bl2, c12, 0, 0, 0);
    c13 = __builtin_amdgcn_mfma_f32_16x16x32_bf16(a1h, bl3, c13, 0, 0, 0);
    c00 = __builtin_amdgcn_mfma_f32_16x16x32_bf16(a0l, bh0, c00, 0, 0, 0);
    c01 = __builtin_amdgcn_mfma_f32_16x16x32_bf16(a0l, bh1, c01, 0, 0, 0);
    c02 = __builtin_amdgcn_mfma_f32_16x16x32_bf16(a0l, bh2, c02, 0, 0, 0);
    c03 = __builtin_amdgcn_mfma_f32_16x16x32_bf16(a0l, bh3, c03, 0, 0, 0);
    c10 = __builtin_amdgcn_mfma_f32_16x16x32_bf16(a1l, bh0, c10, 0, 0, 0);
    c11 = __builtin_amdgcn_mfma_f32_16x16x32_bf16(a1l, bh1, c11, 0, 0, 0);
    c12 = __builtin_amdgcn_mfma_f32_16x16x32_bf16(a1l, bh2, c12, 0, 0, 0);
    c13 = __builtin_amdgcn_mfma_f32_16x16x32_bf16(a1l, bh3, c13, 0, 0, 0);
  }
  int colb = n0 + l15;
  int row0 = m0 + quad * 4;
#pragma unroll
  for (int r = 0; r < 4; ++r) {
    Cm[(row0 + r) * Nn + colb +  0] = c00[r];
    Cm[(row0 + r) * Nn + colb + 16] = c01[r];
    Cm[(row0 + r) * Nn + colb + 32] = c02[r];
    Cm[(row0 + r) * Nn + colb + 48] = c03[r];
    Cm[(row0 + 16 + r) * Nn + colb +  0] = c10[r];
    Cm[(row0 + 16 + r) * Nn + colb + 16] = c11[r];
    Cm[(row0 + 16 + r) * Nn + colb + 32] = c12[r];
    Cm[(row0 + 16 + r) * Nn + colb + 48] = c13[r];
  }
}

// ---------------------------------------------------------------------------
// K5: activations on stage-1 LoRA outputs: tanh(h1w), sigmoid(h1g), in place
// ---------------------------------------------------------------------------
__global__ __launch_bounds__(256) void k_act(float* __restrict__ h1w,
                                             float* __restrict__ h1g) {
  int i = blockIdx.x * 256 + threadIdx.x;   // grid covers BT*128
  if (i < BT * 64)  h1w[i] = tanhf(h1w[i]);
  if (i < BT * 128) h1g[i] = sigf(h1g[i]);
}

// ---------------------------------------------------------------------------
// K6: fused stage-2 LoRA dots (f32) + gates + kk-normalize -> scan inputs.
// ---------------------------------------------------------------------------
__global__ __launch_bounds__(256) void k_prep2(
    const float* __restrict__ h1w, const float* __restrict__ h1a,
    const float* __restrict__ h1v, const float* __restrict__ h1g,
    const float* __restrict__ w2, const float* __restrict__ a2,
    const float* __restrict__ v2, const float* __restrict__ g2,
    const float* __restrict__ w0, const float* __restrict__ a0,
    const float* __restrict__ v0, const float* __restrict__ kkc,
    const float* __restrict__ kac, float* __restrict__ kbuf,
    float* __restrict__ vbuf, const float* __restrict__ vfirst,
    float* __restrict__ dec, float* __restrict__ aw,
    float* __restrict__ bw, float* __restrict__ gval) {
  __shared__ float hs[288][8];   // w:0-63  a:64-127  v:128-159  g:160-287
  int tid = threadIdx.x;
  int c   = blockIdx.x * 256 + tid;
  int t0  = blockIdx.y * 8;
  for (int e = tid; e < 64 * 8;  e += 256) { int d = e >> 3, q = e & 7; hs[d][q]       = h1w[(t0 + q) * 64  + d]; }
  for (int e = tid; e < 64 * 8;  e += 256) { int d = e >> 3, q = e & 7; hs[64 + d][q]  = h1a[(t0 + q) * 64  + d]; }
  for (int e = tid; e < 32 * 8;  e += 256) { int d = e >> 3, q = e & 7; hs[128 + d][q] = h1v[(t0 + q) * 64  + d]; }
  for (int e = tid; e < 128 * 8; e += 256) { int d = e >> 3, q = e & 7; hs[160 + d][q] = h1g[(t0 + q) * 128 + d]; }
  __syncthreads();
  float wacc[8], aacc[8], vacc[8], gacc[8];
#pragma unroll
  for (int q = 0; q < 8; ++q) { wacc[q] = 0.f; aacc[q] = 0.f; vacc[q] = 0.f; gacc[q] = 0.f; }
  for (int d = 0; d < 64; ++d) {
    float wt = w2[d * CC + c];
    float4 h0 = *(const float4*)&hs[d][0];
    float4 h1 = *(const float4*)&hs[d][4];
    wacc[0] = fmaf(h0.x, wt, wacc[0]); wacc[1] = fmaf(h0.y, wt, wacc[1]);
    wacc[2] = fmaf(h0.z, wt, wacc[2]); wacc[3] = fmaf(h0.w, wt, wacc[3]);
    wacc[4] = fmaf(h1.x, wt, wacc[4]); wacc[5] = fmaf(h1.y, wt, wacc[5]);
    wacc[6] = fmaf(h1.z, wt, wacc[6]); wacc[7] = fmaf(h1.w, wt, wacc[7]);
  }
  for (int d = 0; d < 64; ++d) {
    float at = a2[d * CC + c];
    float4 h0 = *(const float4*)&hs[64 + d][0];
    float4 h1 = *(const float4*)&hs[64 + d][4];
    aacc[0] = fmaf(h0.x, at, aacc[0]); aacc[1] = fmaf(h0.y, at, aacc[1]);
    aacc[2] = fmaf(h0.z, at, aacc[2]); aacc[3] = fmaf(h0.w, at, aacc[3]);
    aacc[4] = fmaf(h1.x, at, aacc[4]); aacc[5] = fmaf(h1.y, at, aacc[5]);
    aacc[6] = fmaf(h1.z, at, aacc[6]); aacc[7] = fmaf(h1.w, at, aacc[7]);
  }
  for (int d = 0; d < 32; ++d) {
    float vt = v2[d * CC + c];
    float4 h0 = *(const float4*)&hs[128 + d][0];
    float4 h1 = *(const float4*)&hs[128 + d][4];
    vacc[0] = fmaf(h0.x, vt, vacc[0]); vacc[1] = fmaf(h0.y, vt, vacc[1]);
    vacc[2] = fmaf(h0.z, vt, vacc[2]); vacc[3] = fmaf(h0.w, vt, vacc[3]);
    vacc[4] = fmaf(h1.x, vt, vacc[4]); vacc[5] = fmaf(h1.y, vt, vacc[5]);
    vacc[6] = fmaf(h1.z, vt, vacc[6]); vacc[7] = fmaf(h1.w, vt, vacc[7]);
  }
  for (int d = 0; d < 128; ++d) {
    float gt = g2[d * CC + c];
    float4 h0 = *(const float4*)&hs[160 + d][0];
    float4 h1 = *(const float4*)&hs[160 + d][4];
    gacc[0] = fmaf(h0.x, gt, gacc[0]); gacc[1] = fmaf(h0.y, gt, gacc[1]);
    gacc[2] = fmaf(h0.z, gt, gacc[2]); gacc[3] = fmaf(h0.w, gt, gacc[3]);
    gacc[4] = fmaf(h1.x, gt, gacc[4]); gacc[5] = fmaf(h1.y, gt, gacc[5]);
    gacc[6] = fmaf(h1.z, gt, gacc[6]); gacc[7] = fmaf(h1.w, gt, gacc[7]);
  }
  float w0v = w0[c], a0v = a0[c], v0v = v0[c], kkv = kkc[c], kav = kac[c];
  for (int q = 0; q < 8; ++q) {
    int idx = (t0 + q) * CC + c;
    float kv = kbuf[idx], vv = vbuf[idx], vf = vfirst[idx];
    float d_ = 0.60653065971f * sigf(w0v + wacc[q]);   // sigmoid * e^-0.5
    float as = sigf(a0v + aacc[q]);
    float vs = sigf(v0v + vacc[q]);
    float vm = vv + (vf - vv) * vs;
    float kfv = kv * (1.0f + kav * (as - 1.0f));
    float kku = kv * kkv;
    float s = kku * kku;     // per-head L2 over 64 lanes (wave == head)
    s += __shfl_xor(s, 1);  s += __shfl_xor(s, 2);  s += __shfl_xor(s, 4);
    s += __shfl_xor(s, 8);  s += __shfl_xor(s, 16); s += __shfl_xor(s, 32);
    float nrm = fmaxf(sqrtf(s), 1e-12f);
    float kkn = kku / nrm;
    dec[idx] = d_;
    aw[idx]  = -kkn; bw[idx] = kkn * as;
    kbuf[idx] = kfv; vbuf[idx] = vm; gval[idx] = gacc[q];
  }
}

// ---------------------------------------------------------------------------
// K7: WKV7 scan, 8-wave column-split. Block = 512 thr = 8 waves per (b,h).
// wave w owns state columns [w*8, w*8+8); lane = state row (= output channel).
// ---------------------------------------------------------------------------
__global__ __launch_bounds__(512) void k_scan8(
    const float* __restrict__ rbuf, const float* __restrict__ kf,
    const float* __restrict__ dec, const float* __restrict__ aw,
    const float* __restrict__ bw, const float* __restrict__ vbuf,
    const float* __restrict__ gval, const float* __restrict__ st0,
    const float* __restrict__ rk, const float* __restrict__ gnw,
    const float* __restrict__ gnb,
    __hip_bfloat16* __restrict__ xoh, __hip_bfloat16* __restrict__ xol) {
  int bh = blockIdx.x, b = bh >> 5, h = bh & 31;
  int tid = threadIdx.x, lane = tid & 63, w = tid >> 6;   // w in 0..7
  int col0 = w * 8;
  int chead = h * 64;
  size_t tokbase = (size_t)b * TT * CC + chead;   // + t*CC + ch

  __shared__ float vec[2][5][64];   // [buf][r,k,d,a,b][col-channel]
  __shared__ float vg[2][2][64];    // [buf][v,g][row-channel]
  __shared__ float sa_p[8][65];     // [w][lane], padded
  __shared__ float yp[8][65];
  __shared__ float bon[2][8];
  __shared__ float rkl[64];

  float S[8];
  {
    const float* sp = st0 + ((size_t)bh * 64 + lane) * 64 + col0;
#pragma unroll
    for (int i = 0; i < 8; ++i) S[i] = sp[i];
  }
  if (tid < 64) rkl[tid] = rk[chead + tid];
  float gnwc = gnw[chead + lane], gnbc = gnb[chead + lane];

  int aid = tid >> 6;               // 0..7 ; only aid<7 loads
  int ch  = tid & 63;
  const float* sp7 =
      (aid == 0) ? rbuf : (aid == 1) ? kf : (aid == 2) ? dec :
      (aid == 3) ? aw   : (aid == 4) ? bw : (aid == 5) ? vbuf : gval;
  float* dst0 = (aid < 5) ? &vec[0][aid][ch] : &vg[0][aid - 5][ch];
  float* dst1 = (aid < 5) ? &vec[1][aid][ch] : &vg[1][aid - 5][ch];
  bool loader = (aid < 7);

  if (loader) *dst0 = sp7[tokbase + ch];
  __syncthreads();

  for (int t = 0; t < TT; ++t) {
    int cur = t & 1;
    float pre = 0.f;
    if (loader && t + 1 < TT) pre = sp7[tokbase + (size_t)(t + 1) * CC + ch];

    // ---- phase 1: sa partial over own 8 columns
    {
      const float4* ap = (const float4*)&vec[cur][3][col0];
      float4 a0 = ap[0], a1 = ap[1];
      float sa_part = fmaf(S[0], a0.x, fmaf(S[1], a0.y, fmaf(S[2], a0.z, S[3] * a0.w)))
                    + fmaf(S[4], a1.x, fmaf(S[5], a1.y, fmaf(S[6], a1.z, S[7] * a1.w)));
      sa_p[w][lane] = sa_part;
    }
    __syncthreads();   // B1

    // ---- phase 2: reduce sa, update state, y & bonus partials, stage t+1
    {
      float sa = 0.f;
#pragma unroll
      for (int q = 0; q < 8; ++q) sa += sa_p[q][lane];
      float v_row = vg[cur][0][lane];
      const float4* rp = (const float4*)&vec[cur][0][col0];
      const float4* kp = (const float4*)&vec[cur][1][col0];
      const float4* dp = (const float4*)&vec[cur][2][col0];
      const float4* bp = (const float4*)&vec[cur][4][col0];
      float4 r0 = rp[0], r1 = rp[1];
      float4 k0 = kp[0], k1 = kp[1];
      float4 d0 = dp[0], d1 = dp[1];
      float4 b0 = bp[0], b1 = bp[1];
      float rc[8] = {r0.x, r0.y, r0.z, r0.w, r1.x, r1.y, r1.z, r1.w};
      float kc[8] = {k0.x, k0.y, k0.z, k0.w, k1.x, k1.y, k1.z, k1.w};
      float dc[8] = {d0.x, d0.y, d0.z, d0.w, d1.x, d1.y, d1.z, d1.w};
      float bc[8] = {b0.x, b0.y, b0.z, b0.w, b1.x, b1.y, b1.z, b1.w};
      float yv = 0.f;
#pragma unroll
      for (int i = 0; i < 8; ++i) {
        float s = fmaf(S[i], dc[i], fmaf(sa, bc[i], v_row * kc[i]));
        S[i] = s;
        yv = fmaf(s, rc[i], yv);
      }
      yp[w][lane] = yv;
      if (lane == 0) {
        const float4* qp = (const float4*)&rkl[col0];
        float4 q0 = qp[0], q1 = qp[1];
        float bp_ = rc[0]*kc[0]*q0.x + rc[1]*kc[1]*q0.y + rc[2]*kc[2]*q0.z + rc[3]*kc[3]*q0.w
                  + rc[4]*kc[4]*q1.x + rc[5]*kc[5]*q1.y + rc[6]*kc[6]*q1.z + rc[7]*kc[7]*q1.w;
        bon[cur][w] = bp_;
      }
      if (loader && t + 1 < TT) *((t & 1) ? dst0 : dst1) = pre;  // next buffer
    }
    __syncthreads();   // B2

    // ---- phase 3: wave 0 reduces y, GN + bonus + gate, store
    if (w == 0) {
      float y = 0.f;
#pragma unroll
      for (int q = 0; q < 8; ++q) y += yp[q][lane];
      float bonus = 0.f;
#pragma unroll
      for (int q = 0; q < 8; ++q) bonus += bon[cur][q];
      float s1 = y, s2 = y * y;
#pragma unroll
      for (int off = 1; off < 64; off <<= 1) {
        s1 += __shfl_xor(s1, off);
        s2 += __shfl_xor(s2, off);
      }
      float mean = s1 * (1.0f / 64.0f);
      float var  = s2 * (1.0f / 64.0f) - mean * mean;
      float inv  = rsqrtf(var + GN_EPS);
      float v_row = vg[cur][0][lane];
      float g_row = vg[cur][1][lane];
      float x = (fmaf((y - mean) * inv, gnwc, gnbc) + bonus * v_row) * g_row;
      size_t oidx = tokbase + (size_t)t * CC + lane;
      split_bf16(x, xoh[oidx], xol[oidx]);
    }
  }
}

// ---------------------------------------------------------------------------
extern "C" void kernel_launch(void* const* d_in, const int* in_sizes, int n_in,
                              void* d_out, int out_size, void* d_ws, size_t ws_size,
                              hipStream_t stream) {
  (void)in_sizes; (void)n_in; (void)out_size; (void)ws_size;
  const float* hid    = (const float*)d_in[0];
  const float* shift  = (const float*)d_in[1];
  const float* st0    = (const float*)d_in[2];
  const float* vfirst = (const float*)d_in[3];
  const float* xrc = (const float*)d_in[4];
  const float* xwc = (const float*)d_in[5];
  const float* xkc = (const float*)d_in[6];
  const float* xvc = (const float*)d_in[7];
  const float* xac = (const float*)d_in[8];
  const float* xgc = (const float*)d_in[9];
  const float* w0  = (const float*)d_in[10];
  const float* w1  = (const float*)d_in[11];
  const float* w2  = (const float*)d_in[12];
  const float* a0  = (const float*)d_in[13];
  const float* a1  = (const float*)d_in[14];
  const float* a2  = (const float*)d_in[15];
  const float* v0  = (const float*)d_in[16];
  const float* v1  = (const float*)d_in[17];
  const float* v2  = (const float*)d_in[18];
  const float* g1  = (const float*)d_in[19];
  const float* g2  = (const float*)d_in[20];
  const float* kkc = (const float*)d_in[21];
  const float* kac = (const float*)d_in[22];
  const float* rk  = (const float*)d_in[23];
  const float* Wr  = (const float*)d_in[24];
  const float* Wk  = (const float*)d_in[25];
  const float* Wv  = (const float*)d_in[26];
  const float* Wo  = (const float*)d_in[27];
  const float* gnw = (const float*)d_in[28];
  const float* gnb = (const float*)d_in[29];
  float* out = (float*)d_out;

  char* p = (char*)d_ws;
  auto alloc = [&](size_t n) { char* q = p; p += (n + 255) & ~(size_t)255; return q; };
  const size_t EL = (size_t)BT * CC;

  // --- alias pool (96 MiB): xrh..xvl + Wrh,Wrl dead by k_prep2 time;
  //     db/awb/bwb/gvb (64 MiB) overlay them.
  char* pool = p;
  __hip_bfloat16* xrh = (__hip_bfloat16*)alloc(EL * 2);
  __hip_bfloat16* xrl = (__hip_bfloat16*)alloc(EL * 2);
  __hip_bfloat16* xkh = (__hip_bfloat16*)alloc(EL * 2);
  __hip_bfloat16* xkl = (__hip_bfloat16*)alloc(EL * 2);
  __hip_bfloat16* xvh = (__hip_bfloat16*)alloc(EL * 2);
  __hip_bfloat16* xvl = (__hip_bfloat16*)alloc(EL * 2);
  __hip_bfloat16* Wrh = (__hip_bfloat16*)alloc((size_t)CC * CC * 2);
  __hip_bfloat16* Wrl = (__hip_bfloat16*)alloc((size_t)CC * CC * 2);
  float* db  = (float*)pool;           // overlays xrh+xrl
  float* awb = db + EL;                // overlays xkh+xkl
  float* bwb = db + 2 * EL;            // overlays xvh+xvl
  float* gvb = db + 3 * EL;            // overlays Wrh+Wrl

  __hip_bfloat16* Wkh = (__hip_bfloat16*)alloc((size_t)CC * CC * 2);
  __hip_bfloat16* Wkl = (__hip_bfloat16*)alloc((size_t)CC * CC * 2);
  __hip_bfloat16* Wvh = (__hip_bfloat16*)alloc((size_t)CC * CC * 2);
  __hip_bfloat16* Wvl = (__hip_bfloat16*)alloc((size_t)CC * CC * 2);
  __hip_bfloat16* Woh = (__hip_bfloat16*)alloc((size_t)CC * CC * 2);
  __hip_bfloat16* Wol = (__hip_bfloat16*)alloc((size_t)CC * CC * 2);
  __hip_bfloat16* xw  = (__hip_bfloat16*)alloc(EL * 2);
  __hip_bfloat16* xa  = (__hip_bfloat16*)alloc(EL * 2);
  __hip_bfloat16* xg  = (__hip_bfloat16*)alloc(EL * 2);
  __hip_bfloat16* w1t = (__hip_bfloat16*)alloc((size_t)64  * CC * 2);
  __hip_bfloat16* a1t = (__hip_bfloat16*)alloc((size_t)64  * CC * 2);
  __hip_bfloat16* v1t = (__hip_bfloat16*)alloc((size_t)64  * CC * 2);
  __hip_bfloat16* g1t = (__hip_bfloat16*)alloc((size_t)128 * CC * 2);
  float* rb  = (float*)alloc(EL * 4);
  float* kb  = (float*)alloc(EL * 4);  // raw k, then k_final in place
  float* vb  = (float*)alloc(EL * 4);  // raw v, then v_mix in place
  float* h1w = (float*)alloc((size_t)BT * 64  * 4);
  float* h1a = (float*)alloc((size_t)BT * 64  * 4);
  float* h1v = (float*)alloc((size_t)BT * 64  * 4);
  float* h1g = (float*)alloc((size_t)BT * 128 * 4);
  __hip_bfloat16* xoh = (__hip_bfloat16*)alloc(EL * 2);
  __hip_bfloat16* xol = (__hip_bfloat16*)alloc(EL * 2);
  // total ~204 MiB (fits: 220 MiB known-OK, 268 MiB crashed)

  k_prepx<<<16384, 256, 0, stream>>>(hid, shift, xrc, xwc, xkc, xvc, xac, xgc,
                                     xrh, xrl, xw, xkh, xkl, xvh, xvl, xa, xg);
  k_cvt2<<<16384, 256, 0, stream>>>(Wr, Wrh, Wrl);
  k_cvt2<<<16384, 256, 0, stream>>>(Wk, Wkh, Wkl);
  k_cvt2<<<16384, 256, 0, stream>>>(Wv, Wvh, Wvl);
  k_cvt2<<<16384, 256, 0, stream>>>(Wo, Woh, Wol);
  k_tr<<<512, 256, 0, stream>>>(w1, w1t, 64);
  k_tr<<<512, 256, 0, stream>>>(a1, a1t, 64);
  k_tr<<<512, 256, 0, stream>>>(v1, v1t, 32);
  k_tr<<<1024, 256, 0, stream>>>(g1, g1t, 128);

  // ALL scan-coupled GEMMs split-precision (round-4 lesson: r included)
  k_gemm_bt3<<<dim3(16, 32), 256, 0, stream>>>(xrh, xrl, Wrh, Wrl, rb, BT, CC, CC);
  k_gemm_bt3<<<dim3(16, 32), 256, 0, stream>>>(xkh, xkl, Wkh, Wkl, kb, BT, CC, CC);
  k_gemm_bt3<<<dim3(16, 32), 256, 0, stream>>>(xvh, xvl, Wvh, Wvl, vb, BT, CC, CC);
  k_gemm_bt<<<dim3(16, 1),  256, 0, stream>>>(xw,  w1t, h1w, BT, 64, CC);
  k_gemm_bt<<<dim3(16, 1),  256, 0, stream>>>(xa,  a1t, h1a, BT, 64, CC);
  k_gemm_bt<<<dim3(16, 1),  256, 0, stream>>>(xvh, v1t, h1v, BT, 64, CC);
  k_gemm_bt<<<dim3(16, 2),  256, 0, stream>>>(xg,  g1t, h1g, BT, 128, CC);

  k_act<<<1024, 256, 0, stream>>>(h1w, h1g);
  k_prep2<<<dim3(8, 256), 256, 0, stream>>>(h1w, h1a, h1v, h1g, w2, a2, v2, g2,
                                            w0, a0, v0, kkc, kac, kb, vb, vfirst,
                                            db, awb, bwb, gvb);
  k_scan8<<<64, 512, 0, stream>>>(rb, kb, db, awb, bwb, vb, gvb, st0, rk, gnw, gnb,
                                  xoh, xol);
  k_gemm_bt3<<<dim3(16, 32), 256, 0, stream>>>(xoh, xol, Woh, Wol, out, BT, CC, CC);
}

// Round 7
// 1891.547 us; speedup vs baseline: 1.6892x; 1.2795x over previous
//
#include <hip/hip_runtime.h>
#include <hip/hip_bf16.h>

// Problem constants (RWKV-7 Tmix: B=2, T=1024, C=2048, H=32, N=64)
#define BB 2
#define TT 1024
#define CC 2048
#define HH 32
#define BT 2048          // BB*TT tokens
#define GN_EPS 6.4e-4f   // 1e-5 * 8^2

typedef __attribute__((ext_vector_type(8))) __bf16 bf16x8;
typedef __attribute__((ext_vector_type(4))) float f32x4;

__device__ __forceinline__ float sigf(float x) { return 1.0f / (1.0f + expf(-x)); }

__device__ __forceinline__ void split_bf16(float x, __hip_bfloat16& hi, __hip_bfloat16& lo) {
  __hip_bfloat16 h = __float2bfloat16(x);
  hi = h;
  lo = __float2bfloat16(x - __bfloat162float(h));
}

// ---------------------------------------------------------------------------
// K1: token shift + six lerped projections. r/k/v hi+lo split (all scan
// inputs are error-critical — round-4 lesson); w/a/g plain bf16.
// ---------------------------------------------------------------------------
__global__ __launch_bounds__(256) void k_prepx(
    const float* __restrict__ hid, const float* __restrict__ shift,
    const float* __restrict__ xrc, const float* __restrict__ xwc,
    const float* __restrict__ xkc, const float* __restrict__ xvc,
    const float* __restrict__ xac, const float* __restrict__ xgc,
    __hip_bfloat16* __restrict__ xrh, __hip_bfloat16* __restrict__ xrl,
    __hip_bfloat16* __restrict__ xw,
    __hip_bfloat16* __restrict__ xkh, __hip_bfloat16* __restrict__ xkl,
    __hip_bfloat16* __restrict__ xvh, __hip_bfloat16* __restrict__ xvl,
    __hip_bfloat16* __restrict__ xa, __hip_bfloat16* __restrict__ xg) {
  int idx = blockIdx.x * 256 + threadIdx.x;   // < BT*CC
  int c  = idx & (CC - 1);
  int bt = idx >> 11;
  int t  = bt & (TT - 1);
  int b  = bt >> 10;
  float hcur  = hid[idx];
  float hprev = (t == 0) ? shift[b * CC + c] : hid[idx - CC];
  float xx = hprev - hcur;
  split_bf16(fmaf(xx, xrc[c], hcur), xrh[idx], xrl[idx]);
  split_bf16(fmaf(xx, xkc[c], hcur), xkh[idx], xkl[idx]);
  split_bf16(fmaf(xx, xvc[c], hcur), xvh[idx], xvl[idx]);
  xw[idx] = __float2bfloat16(fmaf(xx, xwc[c], hcur));
  xa[idx] = __float2bfloat16(fmaf(xx, xac[c], hcur));
  xg[idx] = __float2bfloat16(fmaf(xx, xgc[c], hcur));
}

// ---------------------------------------------------------------------------
// K2: f32 -> hi+lo bf16 split (for Wr/Wk/Wv/Wo)
// ---------------------------------------------------------------------------
__global__ __launch_bounds__(256) void k_cvt2(const float* __restrict__ in,
                                              __hip_bfloat16* __restrict__ oh,
                                              __hip_bfloat16* __restrict__ ol) {
  int i = blockIdx.x * 256 + threadIdx.x;
  split_bf16(in[i], oh[i], ol[i]);
}

// ---------------------------------------------------------------------------
// K3: transpose-convert small LoRA "up" weights: in [2048][N0] f32 ->
//     out [NP][2048] bf16 (rows >= N0 zero-padded).
// ---------------------------------------------------------------------------
__global__ __launch_bounds__(256) void k_tr(const float* __restrict__ in,
                                            __hip_bfloat16* __restrict__ out,
                                            int N0) {
  int i = blockIdx.x * 256 + threadIdx.x;   // over NP*2048, grid exact
  int n = i >> 11;
  int k = i & 2047;
  float v = (n < N0) ? in[k * N0 + n] : 0.0f;
  out[i] = __float2bfloat16(v);
}

// ---------------------------------------------------------------------------
// K4: plain bf16 MFMA GEMM, C[M,N] f32 = A[M,K] @ B[N,K]^T
// (LoRA stage-1 only: error-damped through gates)
// ---------------------------------------------------------------------------
__global__ __launch_bounds__(256) void k_gemm_bt(
    const __hip_bfloat16* __restrict__ A, const __hip_bfloat16* __restrict__ Bm,
    float* __restrict__ Cm, int M, int Nn, int K) {
  int tid  = threadIdx.x;
  int lane = tid & 63;
  int wv   = tid >> 6;
  int l15  = lane & 15;
  int quad = lane >> 4;
  int m0 = blockIdx.x * 128 + wv * 32;
  int n0 = blockIdx.y * 64;
  const __hip_bfloat16* ap0 = A + (m0 + l15) * K + quad * 8;
  const __hip_bfloat16* ap1 = ap0 + 16 * K;
  const __hip_bfloat16* bp  = Bm + (n0 + l15) * K + quad * 8;
  f32x4 z = {0.f, 0.f, 0.f, 0.f};
  f32x4 c00 = z, c01 = z, c02 = z, c03 = z;
  f32x4 c10 = z, c11 = z, c12 = z, c13 = z;
  for (int k0 = 0; k0 < K; k0 += 32) {
    bf16x8 a0v = *(const bf16x8*)(ap0 + k0);
    bf16x8 a1v = *(const bf16x8*)(ap1 + k0);
    bf16x8 b0v = *(const bf16x8*)(bp + k0);
    bf16x8 b1v = *(const bf16x8*)(bp + 16 * K + k0);
    bf16x8 b2v = *(const bf16x8*)(bp + 32 * K + k0);
    bf16x8 b3v = *(const bf16x8*)(bp + 48 * K + k0);
    c00 = __builtin_amdgcn_mfma_f32_16x16x32_bf16(a0v, b0v, c00, 0, 0, 0);
    c01 = __builtin_amdgcn_mfma_f32_16x16x32_bf16(a0v, b1v, c01, 0, 0, 0);
    c02 = __builtin_amdgcn_mfma_f32_16x16x32_bf16(a0v, b2v, c02, 0, 0, 0);
    c03 = __builtin_amdgcn_mfma_f32_16x16x32_bf16(a0v, b3v, c03, 0, 0, 0);
    c10 = __builtin_amdgcn_mfma_f32_16x16x32_bf16(a1v, b0v, c10, 0, 0, 0);
    c11 = __builtin_amdgcn_mfma_f32_16x16x32_bf16(a1v, b1v, c11, 0, 0, 0);
    c12 = __builtin_amdgcn_mfma_f32_16x16x32_bf16(a1v, b2v, c12, 0, 0, 0);
    c13 = __builtin_amdgcn_mfma_f32_16x16x32_bf16(a1v, b3v, c13, 0, 0, 0);
  }
  int colb = n0 + l15;
  int row0 = m0 + quad * 4;
#pragma unroll
  for (int r = 0; r < 4; ++r) {
    Cm[(row0 + r) * Nn + colb +  0] = c00[r];
    Cm[(row0 + r) * Nn + colb + 16] = c01[r];
    Cm[(row0 + r) * Nn + colb + 32] = c02[r];
    Cm[(row0 + r) * Nn + colb + 48] = c03[r];
    Cm[(row0 + 16 + r) * Nn + colb +  0] = c10[r];
    Cm[(row0 + 16 + r) * Nn + colb + 16] = c11[r];
    Cm[(row0 + 16 + r) * Nn + colb + 32] = c12[r];
    Cm[(row0 + 16 + r) * Nn + colb + 48] = c13[r];
  }
}

// ---------------------------------------------------------------------------
// K4b: split-precision GEMM: C = (Ah+Al)@(Bh+Bl)^T ~= Ah Bh + Ah Bl + Al Bh.
// ---------------------------------------------------------------------------
__global__ __launch_bounds__(256) void k_gemm_bt3(
    const __hip_bfloat16* __restrict__ Ah, const __hip_bfloat16* __restrict__ Al,
    const __hip_bfloat16* __restrict__ Bh, const __hip_bfloat16* __restrict__ Bl,
    float* __restrict__ Cm, int M, int Nn, int K) {
  int tid  = threadIdx.x;
  int lane = tid & 63;
  int wv   = tid >> 6;
  int l15  = lane & 15;
  int quad = lane >> 4;
  int m0 = blockIdx.x * 128 + wv * 32;
  int n0 = blockIdx.y * 64;
  size_t aoff0 = (size_t)(m0 + l15) * K + quad * 8;
  size_t aoff1 = aoff0 + (size_t)16 * K;
  size_t boff  = (size_t)(n0 + l15) * K + quad * 8;
  f32x4 z = {0.f, 0.f, 0.f, 0.f};
  f32x4 c00 = z, c01 = z, c02 = z, c03 = z;
  f32x4 c10 = z, c11 = z, c12 = z, c13 = z;
  for (int k0 = 0; k0 < K; k0 += 32) {
    bf16x8 a0h = *(const bf16x8*)(Ah + aoff0 + k0);
    bf16x8 a1h = *(const bf16x8*)(Ah + aoff1 + k0);
    bf16x8 a0l = *(const bf16x8*)(Al + aoff0 + k0);
    bf16x8 a1l = *(const bf16x8*)(Al + aoff1 + k0);
    bf16x8 bh0 = *(const bf16x8*)(Bh + boff + k0);
    bf16x8 bh1 = *(const bf16x8*)(Bh + boff + (size_t)16 * K + k0);
    bf16x8 bh2 = *(const bf16x8*)(Bh + boff + (size_t)32 * K + k0);
    bf16x8 bh3 = *(const bf16x8*)(Bh + boff + (size_t)48 * K + k0);
    bf16x8 bl0 = *(const bf16x8*)(Bl + boff + k0);
    bf16x8 bl1 = *(const bf16x8*)(Bl + boff + (size_t)16 * K + k0);
    bf16x8 bl2 = *(const bf16x8*)(Bl + boff + (size_t)32 * K + k0);
    bf16x8 bl3 = *(const bf16x8*)(Bl + boff + (size_t)48 * K + k0);
    c00 = __builtin_amdgcn_mfma_f32_16x16x32_bf16(a0h, bh0, c00, 0, 0, 0);
    c01 = __builtin_amdgcn_mfma_f32_16x16x32_bf16(a0h, bh1, c01, 0, 0, 0);
    c02 = __builtin_amdgcn_mfma_f32_16x16x32_bf16(a0h, bh2, c02, 0, 0, 0);
    c03 = __builtin_amdgcn_mfma_f32_16x16x32_bf16(a0h, bh3, c03, 0, 0, 0);
    c10 = __builtin_amdgcn_mfma_f32_16x16x32_bf16(a1h, bh0, c10, 0, 0, 0);
    c11 = __builtin_amdgcn_mfma_f32_16x16x32_bf16(a1h, bh1, c11, 0, 0, 0);
    c12 = __builtin_amdgcn_mfma_f32_16x16x32_bf16(a1h, bh2, c12, 0, 0, 0);
    c13 = __builtin_amdgcn_mfma_f32_16x16x32_bf16(a1h, bh3, c13, 0, 0, 0);
    c00 = __builtin_amdgcn_mfma_f32_16x16x32_bf16(a0h, bl0, c00, 0, 0, 0);
    c01 = __builtin_amdgcn_mfma_f32_16x16x32_bf16(a0h, bl1, c01, 0, 0, 0);
    c02 = __builtin_amdgcn_mfma_f32_16x16x32_bf16(a0h, bl2, c02, 0, 0, 0);
    c03 = __builtin_amdgcn_mfma_f32_16x16x32_bf16(a0h, bl3, c03, 0, 0, 0);
    c10 = __builtin_amdgcn_mfma_f32_16x16x32_bf16(a1h, bl0, c10, 0, 0, 0);
    c11 = __builtin_amdgcn_mfma_f32_16x16x32_bf16(a1h, bl1, c11, 0, 0, 0);
    c12 = __builtin_amdgcn_mfma_f32_16x16x32_bf16(a1h, bl2, c12, 0, 0, 0);
    c13 = __builtin_amdgcn_mfma_f32_16x16x32_bf16(a1h, bl3, c13, 0, 0, 0);
    c00 = __builtin_amdgcn_mfma_f32_16x16x32_bf16(a0l, bh0, c00, 0, 0, 0);
    c01 = __builtin_amdgcn_mfma_f32_16x16x32_bf16(a0l, bh1, c01, 0, 0, 0);
    c02 = __builtin_amdgcn_mfma_f32_16x16x32_bf16(a0l, bh2, c02, 0, 0, 0);
    c03 = __builtin_amdgcn_mfma_f32_16x16x32_bf16(a0l, bh3, c03, 0, 0, 0);
    c10 = __builtin_amdgcn_mfma_f32_16x16x32_bf16(a1l, bh0, c10, 0, 0, 0);
    c11 = __builtin_amdgcn_mfma_f32_16x16x32_bf16(a1l, bh1, c11, 0, 0, 0);
    c12 = __builtin_amdgcn_mfma_f32_16x16x32_bf16(a1l, bh2, c12, 0, 0, 0);
    c13 = __builtin_amdgcn_mfma_f32_16x16x32_bf16(a1l, bh3, c13, 0, 0, 0);
  }
  int colb = n0 + l15;
  int row0 = m0 + quad * 4;
#pragma unroll
  for (int r = 0; r < 4; ++r) {
    Cm[(row0 + r) * Nn + colb +  0] = c00[r];
    Cm[(row0 + r) * Nn + colb + 16] = c01[r];
    Cm[(row0 + r) * Nn + colb + 32] = c02[r];
    Cm[(row0 + r) * Nn + colb + 48] = c03[r];
    Cm[(row0 + 16 + r) * Nn + colb +  0] = c10[r];
    Cm[(row0 + 16 + r) * Nn + colb + 16] = c11[r];
    Cm[(row0 + 16 + r) * Nn + colb + 32] = c12[r];
    Cm[(row0 + 16 + r) * Nn + colb + 48] = c13[r];
  }
}

// ---------------------------------------------------------------------------
// K5: activations on stage-1 LoRA outputs: tanh(h1w), sigmoid(h1g), in place
// ---------------------------------------------------------------------------
__global__ __launch_bounds__(256) void k_act(float* __restrict__ h1w,
                                             float* __restrict__ h1g) {
  int i = blockIdx.x * 256 + threadIdx.x;   // grid covers BT*128
  if (i < BT * 64)  h1w[i] = tanhf(h1w[i]);
  if (i < BT * 128) h1g[i] = sigf(h1g[i]);
}

// ---------------------------------------------------------------------------
// K6: fused stage-2 LoRA dots (f32) + gates + kk-normalize + per-head bonus
// (sum r*k_final*r_k — S-independent, so computed here not in the scan).
// ---------------------------------------------------------------------------
__global__ __launch_bounds__(256) void k_prep2(
    const float* __restrict__ h1w, const float* __restrict__ h1a,
    const float* __restrict__ h1v, const float* __restrict__ h1g,
    const float* __restrict__ w2, const float* __restrict__ a2,
    const float* __restrict__ v2, const float* __restrict__ g2,
    const float* __restrict__ w0, const float* __restrict__ a0,
    const float* __restrict__ v0, const float* __restrict__ kkc,
    const float* __restrict__ kac, float* __restrict__ kbuf,
    float* __restrict__ vbuf, const float* __restrict__ vfirst,
    const float* __restrict__ rbuf, const float* __restrict__ rk,
    float* __restrict__ dec, float* __restrict__ aw,
    float* __restrict__ bw, float* __restrict__ gval,
    float* __restrict__ bonb) {
  __shared__ float hs[288][8];   // w:0-63  a:64-127  v:128-159  g:160-287
  int tid = threadIdx.x;
  int c   = blockIdx.x * 256 + tid;
  int t0  = blockIdx.y * 8;
  for (int e = tid; e < 64 * 8;  e += 256) { int d = e >> 3, q = e & 7; hs[d][q]       = h1w[(t0 + q) * 64  + d]; }
  for (int e = tid; e < 64 * 8;  e += 256) { int d = e >> 3, q = e & 7; hs[64 + d][q]  = h1a[(t0 + q) * 64  + d]; }
  for (int e = tid; e < 32 * 8;  e += 256) { int d = e >> 3, q = e & 7; hs[128 + d][q] = h1v[(t0 + q) * 64  + d]; }
  for (int e = tid; e < 128 * 8; e += 256) { int d = e >> 3, q = e & 7; hs[160 + d][q] = h1g[(t0 + q) * 128 + d]; }
  __syncthreads();
  float wacc[8], aacc[8], vacc[8], gacc[8];
#pragma unroll
  for (int q = 0; q < 8; ++q) { wacc[q] = 0.f; aacc[q] = 0.f; vacc[q] = 0.f; gacc[q] = 0.f; }
  for (int d = 0; d < 64; ++d) {
    float wt = w2[d * CC + c];
    float4 h0 = *(const float4*)&hs[d][0];
    float4 h1 = *(const float4*)&hs[d][4];
    wacc[0] = fmaf(h0.x, wt, wacc[0]); wacc[1] = fmaf(h0.y, wt, wacc[1]);
    wacc[2] = fmaf(h0.z, wt, wacc[2]); wacc[3] = fmaf(h0.w, wt, wacc[3]);
    wacc[4] = fmaf(h1.x, wt, wacc[4]); wacc[5] = fmaf(h1.y, wt, wacc[5]);
    wacc[6] = fmaf(h1.z, wt, wacc[6]); wacc[7] = fmaf(h1.w, wt, wacc[7]);
  }
  for (int d = 0; d < 64; ++d) {
    float at = a2[d * CC + c];
    float4 h0 = *(const float4*)&hs[64 + d][0];
    float4 h1 = *(const float4*)&hs[64 + d][4];
    aacc[0] = fmaf(h0.x, at, aacc[0]); aacc[1] = fmaf(h0.y, at, aacc[1]);
    aacc[2] = fmaf(h0.z, at, aacc[2]); aacc[3] = fmaf(h0.w, at, aacc[3]);
    aacc[4] = fmaf(h1.x, at, aacc[4]); aacc[5] = fmaf(h1.y, at, aacc[5]);
    aacc[6] = fmaf(h1.z, at, aacc[6]); aacc[7] = fmaf(h1.w, at, aacc[7]);
  }
  for (int d = 0; d < 32; ++d) {
    float vt = v2[d * CC + c];
    float4 h0 = *(const float4*)&hs[128 + d][0];
    float4 h1 = *(const float4*)&hs[128 + d][4];
    vacc[0] = fmaf(h0.x, vt, vacc[0]); vacc[1] = fmaf(h0.y, vt, vacc[1]);
    vacc[2] = fmaf(h0.z, vt, vacc[2]); vacc[3] = fmaf(h0.w, vt, vacc[3]);
    vacc[4] = fmaf(h1.x, vt, vacc[4]); vacc[5] = fmaf(h1.y, vt, vacc[5]);
    vacc[6] = fmaf(h1.z, vt, vacc[6]); vacc[7] = fmaf(h1.w, vt, vacc[7]);
  }
  for (int d = 0; d < 128; ++d) {
    float gt = g2[d * CC + c];
    float4 h0 = *(const float4*)&hs[160 + d][0];
    float4 h1 = *(const float4*)&hs[160 + d][4];
    gacc[0] = fmaf(h0.x, gt, gacc[0]); gacc[1] = fmaf(h0.y, gt, gacc[1]);
    gacc[2] = fmaf(h0.z, gt, gacc[2]); gacc[3] = fmaf(h0.w, gt, gacc[3]);
    gacc[4] = fmaf(h1.x, gt, gacc[4]); gacc[5] = fmaf(h1.y, gt, gacc[5]);
    gacc[6] = fmaf(h1.z, gt, gacc[6]); gacc[7] = fmaf(h1.w, gt, gacc[7]);
  }
  float w0v = w0[c], a0v = a0[c], v0v = v0[c], kkv = kkc[c], kav = kac[c];
  float rkc = rk[c];
  for (int q = 0; q < 8; ++q) {
    int idx = (t0 + q) * CC + c;
    float kv = kbuf[idx], vv = vbuf[idx], vf = vfirst[idx];
    float d_ = 0.60653065971f * sigf(w0v + wacc[q]);   // sigmoid * e^-0.5
    float as = sigf(a0v + aacc[q]);
    float vs = sigf(v0v + vacc[q]);
    float vm = vv + (vf - vv) * vs;
    float kfv = kv * (1.0f + kav * (as - 1.0f));
    float kku = kv * kkv;
    float s = kku * kku;     // per-head L2 over 64 lanes (wave == head)
    s += __shfl_xor(s, 1);  s += __shfl_xor(s, 2);  s += __shfl_xor(s, 4);
    s += __shfl_xor(s, 8);  s += __shfl_xor(s, 16); s += __shfl_xor(s, 32);
    float nrm = fmaxf(sqrtf(s), 1e-12f);
    float kkn = kku / nrm;
    // per-head bonus: sum_c r*k_final*r_k  (wave == head)
    float bon = rbuf[idx] * kfv * rkc;
    bon += __shfl_xor(bon, 1);  bon += __shfl_xor(bon, 2);
    bon += __shfl_xor(bon, 4);  bon += __shfl_xor(bon, 8);
    bon += __shfl_xor(bon, 16); bon += __shfl_xor(bon, 32);
    if ((tid & 63) == 0) bonb[(t0 + q) * HH + (c >> 6)] = bon;
    dec[idx] = d_;
    aw[idx]  = -kkn; bw[idx] = kkn * as;
    kbuf[idx] = kfv; vbuf[idx] = vm; gval[idx] = gacc[q];
  }
}

// ---------------------------------------------------------------------------
// K7: WKV7 scan, ROW-split, barrier-free. Grid = 512 blocks x 64 thr;
// block = one wave = (bh, row-group of 8). lane L: row = rg*8+(L>>3),
// cols = (L&7)*8..+8. sa/y reductions are intra-wave shfl_xor(1,2,4).
// GN/bonus/gate deferred to k_post (raw y -> ybuf). Loads ping-pong
// prefetched one step ahead (unroll-2).
// ---------------------------------------------------------------------------
__global__ __launch_bounds__(64) void k_scan(
    const float* __restrict__ rbuf, const float* __restrict__ kf,
    const float* __restrict__ dec, const float* __restrict__ aw,
    const float* __restrict__ bw, const float* __restrict__ vbuf,
    const float* __restrict__ st0, float* __restrict__ ybuf) {
  int blk = blockIdx.x;                // 0..511
  int bh = blk >> 3, rg = blk & 7;
  int b = bh >> 5, h = bh & 31;
  int lane = threadIdx.x;
  int row = rg * 8 + (lane >> 3);
  int c0  = (lane & 7) * 8;
  size_t tokbase = (size_t)b * TT * CC + h * 64;

  float S[8];
  {
    const float* sp = st0 + ((size_t)bh * 64 + row) * 64 + c0;
#pragma unroll
    for (int i = 0; i < 8; ++i) S[i] = sp[i];
  }

  bool writer = ((lane & 7) == 0);
  float* yout = ybuf + tokbase + row;

#define LOADT(T, vr0, vr1, vk0, vk1, vd0, vd1, va0, va1, vb0, vb1, VV)   \
  { size_t o = tokbase + (size_t)(T) * CC;                               \
    const float* pc = rbuf + o + c0;                                     \
    vr0 = *(const float4*)pc;      vr1 = *(const float4*)(pc + 4);       \
    pc = kf + o + c0;                                                    \
    vk0 = *(const float4*)pc;      vk1 = *(const float4*)(pc + 4);       \
    pc = dec + o + c0;                                                   \
    vd0 = *(const float4*)pc;      vd1 = *(const float4*)(pc + 4);       \
    pc = aw + o + c0;                                                    \
    va0 = *(const float4*)pc;      va1 = *(const float4*)(pc + 4);       \
    pc = bw + o + c0;                                                    \
    vb0 = *(const float4*)pc;      vb1 = *(const float4*)(pc + 4);       \
    VV = vbuf[o + row]; }

  auto step = [&](int T, float4 xr0, float4 xr1, float4 xk0, float4 xk1,
                  float4 xd0, float4 xd1, float4 xa0, float4 xa1,
                  float4 xb0, float4 xb1, float vvv) {
    // sa partial over own cols
    float sa = fmaf(S[0], xa0.x, fmaf(S[1], xa0.y, fmaf(S[2], xa0.z, S[3] * xa0.w)))
             + fmaf(S[4], xa1.x, fmaf(S[5], xa1.y, fmaf(S[6], xa1.z, S[7] * xa1.w)));
    sa += __shfl_xor(sa, 1); sa += __shfl_xor(sa, 2); sa += __shfl_xor(sa, 4);
    float dc[8] = {xd0.x, xd0.y, xd0.z, xd0.w, xd1.x, xd1.y, xd1.z, xd1.w};
    float bc[8] = {xb0.x, xb0.y, xb0.z, xb0.w, xb1.x, xb1.y, xb1.z, xb1.w};
    float kc[8] = {xk0.x, xk0.y, xk0.z, xk0.w, xk1.x, xk1.y, xk1.z, xk1.w};
    float rc[8] = {xr0.x, xr0.y, xr0.z, xr0.w, xr1.x, xr1.y, xr1.z, xr1.w};
    float y = 0.f;
#pragma unroll
    for (int i = 0; i < 8; ++i) {
      float s = fmaf(S[i], dc[i], fmaf(sa, bc[i], vvv * kc[i]));
      S[i] = s;
      y = fmaf(s, rc[i], y);
    }
    y += __shfl_xor(y, 1); y += __shfl_xor(y, 2); y += __shfl_xor(y, 4);
    if (writer) yout[(size_t)T * CC] = y;
  };

  float4 ra0, rb0, ka0, kb0, da0, db0, aa0, ab0, ea0, eb0; float vv0;
  float4 ra1, rb1, ka1, kb1, da1, db1, aa1, ab1, ea1, eb1; float vv1;
  LOADT(0, ra0, rb0, ka0, kb0, da0, db0, aa0, ab0, ea0, eb0, vv0);
  for (int t = 0; t < TT; t += 2) {
    LOADT(t + 1, ra1, rb1, ka1, kb1, da1, db1, aa1, ab1, ea1, eb1, vv1);
    step(t, ra0, rb0, ka0, kb0, da0, db0, aa0, ab0, ea0, eb0, vv0);
    if (t + 2 < TT)
      LOADT(t + 2, ra0, rb0, ka0, kb0, da0, db0, aa0, ab0, ea0, eb0, vv0);
    step(t + 1, ra1, rb1, ka1, kb1, da1, db1, aa1, ab1, ea1, eb1, vv1);
  }
#undef LOADT
}

// ---------------------------------------------------------------------------
// K8: post-scan epilogue: GroupNorm + bonus + g-gate, fully parallel.
// Block 256 = 4 waves; wave = one (token, head).
// ---------------------------------------------------------------------------
__global__ __launch_bounds__(256) void k_post(
    const float* __restrict__ ybuf, const float* __restrict__ vb,
    const float* __restrict__ gvb, const float* __restrict__ bonb,
    const float* __restrict__ gnw, const float* __restrict__ gnb,
    __hip_bfloat16* __restrict__ xoh, __hip_bfloat16* __restrict__ xol) {
  int tid = threadIdx.x, wv = tid >> 6, lane = tid & 63;
  int id = blockIdx.x * 4 + wv;        // 0..BT*HH-1
  int bt = id >> 5, h = id & 31;
  size_t base = (size_t)bt * CC + h * 64 + lane;
  float y = ybuf[base];
  float s1 = y, s2 = y * y;
#pragma unroll
  for (int off = 1; off < 64; off <<= 1) {
    s1 += __shfl_xor(s1, off);
    s2 += __shfl_xor(s2, off);
  }
  float mean = s1 * (1.0f / 64.0f);
  float var  = s2 * (1.0f / 64.0f) - mean * mean;
  float inv  = rsqrtf(var + GN_EPS);
  float x = fmaf((y - mean) * inv, gnw[h * 64 + lane], gnb[h * 64 + lane])
          + bonb[bt * HH + h] * vb[base];
  split_bf16(x * gvb[base], xoh[base], xol[base]);
}

// ---------------------------------------------------------------------------
extern "C" void kernel_launch(void* const* d_in, const int* in_sizes, int n_in,
                              void* d_out, int out_size, void* d_ws, size_t ws_size,
                              hipStream_t stream) {
  (void)in_sizes; (void)n_in; (void)out_size; (void)ws_size;
  const float* hid    = (const float*)d_in[0];
  const float* shift  = (const float*)d_in[1];
  const float* st0    = (const float*)d_in[2];
  const float* vfirst = (const float*)d_in[3];
  const float* xrc = (const float*)d_in[4];
  const float* xwc = (const float*)d_in[5];
  const float* xkc = (const float*)d_in[6];
  const float* xvc = (const float*)d_in[7];
  const float* xac = (const float*)d_in[8];
  const float* xgc = (const float*)d_in[9];
  const float* w0  = (const float*)d_in[10];
  const float* w1  = (const float*)d_in[11];
  const float* w2  = (const float*)d_in[12];
  const float* a0  = (const float*)d_in[13];
  const float* a1  = (const float*)d_in[14];
  const float* a2  = (const float*)d_in[15];
  const float* v0  = (const float*)d_in[16];
  const float* v1  = (const float*)d_in[17];
  const float* v2  = (const float*)d_in[18];
  const float* g1  = (const float*)d_in[19];
  const float* g2  = (const float*)d_in[20];
  const float* kkc = (const float*)d_in[21];
  const float* kac = (const float*)d_in[22];
  const float* rk  = (const float*)d_in[23];
  const float* Wr  = (const float*)d_in[24];
  const float* Wk  = (const float*)d_in[25];
  const float* Wv  = (const float*)d_in[26];
  const float* Wo  = (const float*)d_in[27];
  const float* gnw = (const float*)d_in[28];
  const float* gnb = (const float*)d_in[29];
  float* out = (float*)d_out;

  char* p = (char*)d_ws;
  auto alloc = [&](size_t n) { char* q = p; p += (n + 255) & ~(size_t)255; return q; };
  const size_t EL = (size_t)BT * CC;

  // --- alias pool (96 MiB): xrh..xvl + Wrh,Wrl dead by k_prep2 time;
  //     db/awb/bwb/gvb (64 MiB) overlay them.
  char* pool = p;
  __hip_bfloat16* xrh = (__hip_bfloat16*)alloc(EL * 2);
  __hip_bfloat16* xrl = (__hip_bfloat16*)alloc(EL * 2);
  __hip_bfloat16* xkh = (__hip_bfloat16*)alloc(EL * 2);
  __hip_bfloat16* xkl = (__hip_bfloat16*)alloc(EL * 2);
  __hip_bfloat16* xvh = (__hip_bfloat16*)alloc(EL * 2);
  __hip_bfloat16* xvl = (__hip_bfloat16*)alloc(EL * 2);
  __hip_bfloat16* Wrh = (__hip_bfloat16*)alloc((size_t)CC * CC * 2);
  __hip_bfloat16* Wrl = (__hip_bfloat16*)alloc((size_t)CC * CC * 2);
  float* db  = (float*)pool;           // overlays xrh+xrl
  float* awb = db + EL;                // overlays xkh+xkl
  float* bwb = db + 2 * EL;            // overlays xvh+xvl
  float* gvb = db + 3 * EL;            // overlays Wrh+Wrl

  __hip_bfloat16* Wkh = (__hip_bfloat16*)alloc((size_t)CC * CC * 2);
  __hip_bfloat16* Wkl = (__hip_bfloat16*)alloc((size_t)CC * CC * 2);
  float* ybuf = (float*)Wkh;           // overlays Wkh+Wkl (dead after k-GEMM)

  __hip_bfloat16* Wvh = (__hip_bfloat16*)alloc((size_t)CC * CC * 2);
  __hip_bfloat16* Wvl = (__hip_bfloat16*)alloc((size_t)CC * CC * 2);
  __hip_bfloat16* Woh = (__hip_bfloat16*)alloc((size_t)CC * CC * 2);
  __hip_bfloat16* Wol = (__hip_bfloat16*)alloc((size_t)CC * CC * 2);
  __hip_bfloat16* xw  = (__hip_bfloat16*)alloc(EL * 2);
  __hip_bfloat16* xa  = (__hip_bfloat16*)alloc(EL * 2);
  __hip_bfloat16* xg  = (__hip_bfloat16*)alloc(EL * 2);
  __hip_bfloat16* w1t = (__hip_bfloat16*)alloc((size_t)64  * CC * 2);
  __hip_bfloat16* a1t = (__hip_bfloat16*)alloc((size_t)64  * CC * 2);
  __hip_bfloat16* v1t = (__hip_bfloat16*)alloc((size_t)64  * CC * 2);
  __hip_bfloat16* g1t = (__hip_bfloat16*)alloc((size_t)128 * CC * 2);
  float* rb  = (float*)alloc(EL * 4);
  float* kb  = (float*)alloc(EL * 4);  // raw k, then k_final in place
  float* vb  = (float*)alloc(EL * 4);  // raw v, then v_mix in place
  float* h1w = (float*)alloc((size_t)BT * 64  * 4);
  float* h1a = (float*)alloc((size_t)BT * 64  * 4);
  float* h1v = (float*)alloc((size_t)BT * 64  * 4);
  float* h1g = (float*)alloc((size_t)BT * 128 * 4);
  __hip_bfloat16* xoh = (__hip_bfloat16*)alloc(EL * 2);
  __hip_bfloat16* xol = (__hip_bfloat16*)alloc(EL * 2);
  float* bonb = (float*)alloc((size_t)BT * HH * 4);   // per-(token,head) bonus
  // total ~204.5 MiB (fits: 220 MiB known-OK, 268 MiB crashed)

  k_prepx<<<16384, 256, 0, stream>>>(hid, shift, xrc, xwc, xkc, xvc, xac, xgc,
                                     xrh, xrl, xw, xkh, xkl, xvh, xvl, xa, xg);
  k_cvt2<<<16384, 256, 0, stream>>>(Wr, Wrh, Wrl);
  k_cvt2<<<16384, 256, 0, stream>>>(Wk, Wkh, Wkl);
  k_cvt2<<<16384, 256, 0, stream>>>(Wv, Wvh, Wvl);
  k_cvt2<<<16384, 256, 0, stream>>>(Wo, Woh, Wol);
  k_tr<<<512, 256, 0, stream>>>(w1, w1t, 64);
  k_tr<<<512, 256, 0, stream>>>(a1, a1t, 64);
  k_tr<<<512, 256, 0, stream>>>(v1, v1t, 32);
  k_tr<<<1024, 256, 0, stream>>>(g1, g1t, 128);

  k_gemm_bt3<<<dim3(16, 32), 256, 0, stream>>>(xrh, xrl, Wrh, Wrl, rb, BT, CC, CC);
  k_gemm_bt3<<<dim3(16, 32), 256, 0, stream>>>(xkh, xkl, Wkh, Wkl, kb, BT, CC, CC);
  k_gemm_bt3<<<dim3(16, 32), 256, 0, stream>>>(xvh, xvl, Wvh, Wvl, vb, BT, CC, CC);
  k_gemm_bt<<<dim3(16, 1),  256, 0, stream>>>(xw,  w1t, h1w, BT, 64, CC);
  k_gemm_bt<<<dim3(16, 1),  256, 0, stream>>>(xa,  a1t, h1a, BT, 64, CC);
  k_gemm_bt<<<dim3(16, 1),  256, 0, stream>>>(xvh, v1t, h1v, BT, 64, CC);
  k_gemm_bt<<<dim3(16, 2),  256, 0, stream>>>(xg,  g1t, h1g, BT, 128, CC);

  k_act<<<1024, 256, 0, stream>>>(h1w, h1g);
  // from here: xrh..xvl / Wrh,Wrl dead (db/awb/bwb/gvb overlay);
  //            Wkh/Wkl dead (ybuf overlay)
  k_prep2<<<dim3(8, 256), 256, 0, stream>>>(h1w, h1a, h1v, h1g, w2, a2, v2, g2,
                                            w0, a0, v0, kkc, kac, kb, vb, vfirst,
                                            rb, rk, db, awb, bwb, gvb, bonb);
  k_scan<<<512, 64, 0, stream>>>(rb, kb, db, awb, bwb, vb, st0, ybuf);
  k_post<<<16384, 256, 0, stream>>>(ybuf, vb, gvb, bonb, gnw, gnb, xoh, xol);
  k_gemm_bt3<<<dim3(16, 32), 256, 0, stream>>>(xoh, xol, Woh, Wol, out, BT, CC, CC);
}

// Round 8
// 1855.665 us; speedup vs baseline: 1.7219x; 1.0193x over previous
//
#include <hip/hip_runtime.h>
#include <hip/hip_bf16.h>

// Problem constants (RWKV-7 Tmix: B=2, T=1024, C=2048, H=32, N=64)
#define BB 2
#define TT 1024
#define CC 2048
#define HH 32
#define BT 2048          // BB*TT tokens
#define GN_EPS 6.4e-4f   // 1e-5 * 8^2

typedef __attribute__((ext_vector_type(8))) __bf16 bf16x8;
typedef __attribute__((ext_vector_type(4))) float f32x4;

__device__ __forceinline__ float sigf(float x) { return 1.0f / (1.0f + expf(-x)); }

__device__ __forceinline__ void split_bf16(float x, __hip_bfloat16& hi, __hip_bfloat16& lo) {
  __hip_bfloat16 h = __float2bfloat16(x);
  hi = h;
  lo = __float2bfloat16(x - __bfloat162float(h));
}

// ---------------------------------------------------------------------------
// K1: token shift + six lerped projections. r/k/v hi+lo split (all scan
// inputs are error-critical — round-4 lesson); w/a/g plain bf16.
// ---------------------------------------------------------------------------
__global__ __launch_bounds__(256) void k_prepx(
    const float* __restrict__ hid, const float* __restrict__ shift,
    const float* __restrict__ xrc, const float* __restrict__ xwc,
    const float* __restrict__ xkc, const float* __restrict__ xvc,
    const float* __restrict__ xac, const float* __restrict__ xgc,
    __hip_bfloat16* __restrict__ xrh, __hip_bfloat16* __restrict__ xrl,
    __hip_bfloat16* __restrict__ xw,
    __hip_bfloat16* __restrict__ xkh, __hip_bfloat16* __restrict__ xkl,
    __hip_bfloat16* __restrict__ xvh, __hip_bfloat16* __restrict__ xvl,
    __hip_bfloat16* __restrict__ xa, __hip_bfloat16* __restrict__ xg) {
  int idx = blockIdx.x * 256 + threadIdx.x;   // < BT*CC
  int c  = idx & (CC - 1);
  int bt = idx >> 11;
  int t  = bt & (TT - 1);
  int b  = bt >> 10;
  float hcur  = hid[idx];
  float hprev = (t == 0) ? shift[b * CC + c] : hid[idx - CC];
  float xx = hprev - hcur;
  split_bf16(fmaf(xx, xrc[c], hcur), xrh[idx], xrl[idx]);
  split_bf16(fmaf(xx, xkc[c], hcur), xkh[idx], xkl[idx]);
  split_bf16(fmaf(xx, xvc[c], hcur), xvh[idx], xvl[idx]);
  xw[idx] = __float2bfloat16(fmaf(xx, xwc[c], hcur));
  xa[idx] = __float2bfloat16(fmaf(xx, xac[c], hcur));
  xg[idx] = __float2bfloat16(fmaf(xx, xgc[c], hcur));
}

// ---------------------------------------------------------------------------
// K2: f32 -> hi+lo bf16 split (for Wr/Wk/Wv/Wo)
// ---------------------------------------------------------------------------
__global__ __launch_bounds__(256) void k_cvt2(const float* __restrict__ in,
                                              __hip_bfloat16* __restrict__ oh,
                                              __hip_bfloat16* __restrict__ ol) {
  int i = blockIdx.x * 256 + threadIdx.x;
  split_bf16(in[i], oh[i], ol[i]);
}

// ---------------------------------------------------------------------------
// K3: transpose-convert small LoRA "up" weights: in [2048][N0] f32 ->
//     out [NP][2048] bf16 (rows >= N0 zero-padded).
// ---------------------------------------------------------------------------
__global__ __launch_bounds__(256) void k_tr(const float* __restrict__ in,
                                            __hip_bfloat16* __restrict__ out,
                                            int N0) {
  int i = blockIdx.x * 256 + threadIdx.x;   // over NP*2048, grid exact
  int n = i >> 11;
  int k = i & 2047;
  float v = (n < N0) ? in[k * N0 + n] : 0.0f;
  out[i] = __float2bfloat16(v);
}

// ---------------------------------------------------------------------------
// K4: plain bf16 MFMA GEMM, C[M,N] f32 = A[M,K] @ B[N,K]^T
// (LoRA stage-1 only: error-damped through gates)
// ---------------------------------------------------------------------------
__global__ __launch_bounds__(256) void k_gemm_bt(
    const __hip_bfloat16* __restrict__ A, const __hip_bfloat16* __restrict__ Bm,
    float* __restrict__ Cm, int M, int Nn, int K) {
  int tid  = threadIdx.x;
  int lane = tid & 63;
  int wv   = tid >> 6;
  int l15  = lane & 15;
  int quad = lane >> 4;
  int m0 = blockIdx.x * 128 + wv * 32;
  int n0 = blockIdx.y * 64;
  const __hip_bfloat16* ap0 = A + (m0 + l15) * K + quad * 8;
  const __hip_bfloat16* ap1 = ap0 + 16 * K;
  const __hip_bfloat16* bp  = Bm + (n0 + l15) * K + quad * 8;
  f32x4 z = {0.f, 0.f, 0.f, 0.f};
  f32x4 c00 = z, c01 = z, c02 = z, c03 = z;
  f32x4 c10 = z, c11 = z, c12 = z, c13 = z;
  for (int k0 = 0; k0 < K; k0 += 32) {
    bf16x8 a0v = *(const bf16x8*)(ap0 + k0);
    bf16x8 a1v = *(const bf16x8*)(ap1 + k0);
    bf16x8 b0v = *(const bf16x8*)(bp + k0);
    bf16x8 b1v = *(const bf16x8*)(bp + 16 * K + k0);
    bf16x8 b2v = *(const bf16x8*)(bp + 32 * K + k0);
    bf16x8 b3v = *(const bf16x8*)(bp + 48 * K + k0);
    c00 = __builtin_amdgcn_mfma_f32_16x16x32_bf16(a0v, b0v, c00, 0, 0, 0);
    c01 = __builtin_amdgcn_mfma_f32_16x16x32_bf16(a0v, b1v, c01, 0, 0, 0);
    c02 = __builtin_amdgcn_mfma_f32_16x16x32_bf16(a0v, b2v, c02, 0, 0, 0);
    c03 = __builtin_amdgcn_mfma_f32_16x16x32_bf16(a0v, b3v, c03, 0, 0, 0);
    c10 = __builtin_amdgcn_mfma_f32_16x16x32_bf16(a1v, b0v, c10, 0, 0, 0);
    c11 = __builtin_amdgcn_mfma_f32_16x16x32_bf16(a1v, b1v, c11, 0, 0, 0);
    c12 = __builtin_amdgcn_mfma_f32_16x16x32_bf16(a1v, b2v, c12, 0, 0, 0);
    c13 = __builtin_amdgcn_mfma_f32_16x16x32_bf16(a1v, b3v, c13, 0, 0, 0);
  }
  int colb = n0 + l15;
  int row0 = m0 + quad * 4;
#pragma unroll
  for (int r = 0; r < 4; ++r) {
    Cm[(row0 + r) * Nn + colb +  0] = c00[r];
    Cm[(row0 + r) * Nn + colb + 16] = c01[r];
    Cm[(row0 + r) * Nn + colb + 32] = c02[r];
    Cm[(row0 + r) * Nn + colb + 48] = c03[r];
    Cm[(row0 + 16 + r) * Nn + colb +  0] = c10[r];
    Cm[(row0 + 16 + r) * Nn + colb + 16] = c11[r];
    Cm[(row0 + 16 + r) * Nn + colb + 32] = c12[r];
    Cm[(row0 + 16 + r) * Nn + colb + 48] = c13[r];
  }
}

// ---------------------------------------------------------------------------
// K4b: split-precision GEMM: C = (Ah+Al)@(Bh+Bl)^T ~= Ah Bh + Ah Bl + Al Bh.
// ---------------------------------------------------------------------------
__global__ __launch_bounds__(256) void k_gemm_bt3(
    const __hip_bfloat16* __restrict__ Ah, const __hip_bfloat16* __restrict__ Al,
    const __hip_bfloat16* __restrict__ Bh, const __hip_bfloat16* __restrict__ Bl,
    float* __restrict__ Cm, int M, int Nn, int K) {
  int tid  = threadIdx.x;
  int lane = tid & 63;
  int wv   = tid >> 6;
  int l15  = lane & 15;
  int quad = lane >> 4;
  int m0 = blockIdx.x * 128 + wv * 32;
  int n0 = blockIdx.y * 64;
  size_t aoff0 = (size_t)(m0 + l15) * K + quad * 8;
  size_t aoff1 = aoff0 + (size_t)16 * K;
  size_t boff  = (size_t)(n0 + l15) * K + quad * 8;
  f32x4 z = {0.f, 0.f, 0.f, 0.f};
  f32x4 c00 = z, c01 = z, c02 = z, c03 = z;
  f32x4 c10 = z, c11 = z, c12 = z, c13 = z;
  for (int k0 = 0; k0 < K; k0 += 32) {
    bf16x8 a0h = *(const bf16x8*)(Ah + aoff0 + k0);
    bf16x8 a1h = *(const bf16x8*)(Ah + aoff1 + k0);
    bf16x8 a0l = *(const bf16x8*)(Al + aoff0 + k0);
    bf16x8 a1l = *(const bf16x8*)(Al + aoff1 + k0);
    bf16x8 bh0 = *(const bf16x8*)(Bh + boff + k0);
    bf16x8 bh1 = *(const bf16x8*)(Bh + boff + (size_t)16 * K + k0);
    bf16x8 bh2 = *(const bf16x8*)(Bh + boff + (size_t)32 * K + k0);
    bf16x8 bh3 = *(const bf16x8*)(Bh + boff + (size_t)48 * K + k0);
    bf16x8 bl0 = *(const bf16x8*)(Bl + boff + k0);
    bf16x8 bl1 = *(const bf16x8*)(Bl + boff + (size_t)16 * K + k0);
    bf16x8 bl2 = *(const bf16x8*)(Bl + boff + (size_t)32 * K + k0);
    bf16x8 bl3 = *(const bf16x8*)(Bl + boff + (size_t)48 * K + k0);
    c00 = __builtin_amdgcn_mfma_f32_16x16x32_bf16(a0h, bh0, c00, 0, 0, 0);
    c01 = __builtin_amdgcn_mfma_f32_16x16x32_bf16(a0h, bh1, c01, 0, 0, 0);
    c02 = __builtin_amdgcn_mfma_f32_16x16x32_bf16(a0h, bh2, c02, 0, 0, 0);
    c03 = __builtin_amdgcn_mfma_f32_16x16x32_bf16(a0h, bh3, c03, 0, 0, 0);
    c10 = __builtin_amdgcn_mfma_f32_16x16x32_bf16(a1h, bh0, c10, 0, 0, 0);
    c11 = __builtin_amdgcn_mfma_f32_16x16x32_bf16(a1h, bh1, c11, 0, 0, 0);
    c12 = __builtin_amdgcn_mfma_f32_16x16x32_bf16(a1h, bh2, c12, 0, 0, 0);
    c13 = __builtin_amdgcn_mfma_f32_16x16x32_bf16(a1h, bh3, c13, 0, 0, 0);
    c00 = __builtin_amdgcn_mfma_f32_16x16x32_bf16(a0h, bl0, c00, 0, 0, 0);
    c01 = __builtin_amdgcn_mfma_f32_16x16x32_bf16(a0h, bl1, c01, 0, 0, 0);
    c02 = __builtin_amdgcn_mfma_f32_16x16x32_bf16(a0h, bl2, c02, 0, 0, 0);
    c03 = __builtin_amdgcn_mfma_f32_16x16x32_bf16(a0h, bl3, c03, 0, 0, 0);
    c10 = __builtin_amdgcn_mfma_f32_16x16x32_bf16(a1h, bl0, c10, 0, 0, 0);
    c11 = __builtin_amdgcn_mfma_f32_16x16x32_bf16(a1h, bl1, c11, 0, 0, 0);
    c12 = __builtin_amdgcn_mfma_f32_16x16x32_bf16(a1h, bl2, c12, 0, 0, 0);
    c13 = __builtin_amdgcn_mfma_f32_16x16x32_bf16(a1h, bl3, c13, 0, 0, 0);
    c00 = __builtin_amdgcn_mfma_f32_16x16x32_bf16(a0l, bh0, c00, 0, 0, 0);
    c01 = __builtin_amdgcn_mfma_f32_16x16x32_bf16(a0l, bh1, c01, 0, 0, 0);
    c02 = __builtin_amdgcn_mfma_f32_16x16x32_bf16(a0l, bh2, c02, 0, 0, 0);
    c03 = __builtin_amdgcn_mfma_f32_16x16x32_bf16(a0l, bh3, c03, 0, 0, 0);
    c10 = __builtin_amdgcn_mfma_f32_16x16x32_bf16(a1l, bh0, c10, 0, 0, 0);
    c11 = __builtin_amdgcn_mfma_f32_16x16x32_bf16(a1l, bh1, c11, 0, 0, 0);
    c12 = __builtin_amdgcn_mfma_f32_16x16x32_bf16(a1l, bh2, c12, 0, 0, 0);
    c13 = __builtin_amdgcn_mfma_f32_16x16x32_bf16(a1l, bh3, c13, 0, 0, 0);
  }
  int colb = n0 + l15;
  int row0 = m0 + quad * 4;
#pragma unroll
  for (int r = 0; r < 4; ++r) {
    Cm[(row0 + r) * Nn + colb +  0] = c00[r];
    Cm[(row0 + r) * Nn + colb + 16] = c01[r];
    Cm[(row0 + r) * Nn + colb + 32] = c02[r];
    Cm[(row0 + r) * Nn + colb + 48] = c03[r];
    Cm[(row0 + 16 + r) * Nn + colb +  0] = c10[r];
    Cm[(row0 + 16 + r) * Nn + colb + 16] = c11[r];
    Cm[(row0 + 16 + r) * Nn + colb + 32] = c12[r];
    Cm[(row0 + 16 + r) * Nn + colb + 48] = c13[r];
  }
}

// ---------------------------------------------------------------------------
// K5: activations on stage-1 LoRA outputs: tanh(h1w), sigmoid(h1g), in place
// ---------------------------------------------------------------------------
__global__ __launch_bounds__(256) void k_act(float* __restrict__ h1w,
                                             float* __restrict__ h1g) {
  int i = blockIdx.x * 256 + threadIdx.x;   // grid covers BT*128
  if (i < BT * 64)  h1w[i] = tanhf(h1w[i]);
  if (i < BT * 128) h1g[i] = sigf(h1g[i]);
}

// ---------------------------------------------------------------------------
// K6: fused stage-2 LoRA dots (f32) + gates + kk-normalize + per-head bonus
// (sum r*k_final*r_k — S-independent, so computed here not in the scan).
// ---------------------------------------------------------------------------
__global__ __launch_bounds__(256) void k_prep2(
    const float* __restrict__ h1w, const float* __restrict__ h1a,
    const float* __restrict__ h1v, const float* __restrict__ h1g,
    const float* __restrict__ w2, const float* __restrict__ a2,
    const float* __restrict__ v2, const float* __restrict__ g2,
    const float* __restrict__ w0, const float* __restrict__ a0,
    const float* __restrict__ v0, const float* __restrict__ kkc,
    const float* __restrict__ kac, float* __restrict__ kbuf,
    float* __restrict__ vbuf, const float* __restrict__ vfirst,
    const float* __restrict__ rbuf, const float* __restrict__ rk,
    float* __restrict__ dec, float* __restrict__ aw,
    float* __restrict__ bw, float* __restrict__ gval,
    float* __restrict__ bonb) {
  __shared__ float hs[288][8];   // w:0-63  a:64-127  v:128-159  g:160-287
  int tid = threadIdx.x;
  int c   = blockIdx.x * 256 + tid;
  int t0  = blockIdx.y * 8;
  for (int e = tid; e < 64 * 8;  e += 256) { int d = e >> 3, q = e & 7; hs[d][q]       = h1w[(t0 + q) * 64  + d]; }
  for (int e = tid; e < 64 * 8;  e += 256) { int d = e >> 3, q = e & 7; hs[64 + d][q]  = h1a[(t0 + q) * 64  + d]; }
  for (int e = tid; e < 32 * 8;  e += 256) { int d = e >> 3, q = e & 7; hs[128 + d][q] = h1v[(t0 + q) * 64  + d]; }
  for (int e = tid; e < 128 * 8; e += 256) { int d = e >> 3, q = e & 7; hs[160 + d][q] = h1g[(t0 + q) * 128 + d]; }
  __syncthreads();
  float wacc[8], aacc[8], vacc[8], gacc[8];
#pragma unroll
  for (int q = 0; q < 8; ++q) { wacc[q] = 0.f; aacc[q] = 0.f; vacc[q] = 0.f; gacc[q] = 0.f; }
  for (int d = 0; d < 64; ++d) {
    float wt = w2[d * CC + c];
    float4 h0 = *(const float4*)&hs[d][0];
    float4 h1 = *(const float4*)&hs[d][4];
    wacc[0] = fmaf(h0.x, wt, wacc[0]); wacc[1] = fmaf(h0.y, wt, wacc[1]);
    wacc[2] = fmaf(h0.z, wt, wacc[2]); wacc[3] = fmaf(h0.w, wt, wacc[3]);
    wacc[4] = fmaf(h1.x, wt, wacc[4]); wacc[5] = fmaf(h1.y, wt, wacc[5]);
    wacc[6] = fmaf(h1.z, wt, wacc[6]); wacc[7] = fmaf(h1.w, wt, wacc[7]);
  }
  for (int d = 0; d < 64; ++d) {
    float at = a2[d * CC + c];
    float4 h0 = *(const float4*)&hs[64 + d][0];
    float4 h1 = *(const float4*)&hs[64 + d][4];
    aacc[0] = fmaf(h0.x, at, aacc[0]); aacc[1] = fmaf(h0.y, at, aacc[1]);
    aacc[2] = fmaf(h0.z, at, aacc[2]); aacc[3] = fmaf(h0.w, at, aacc[3]);
    aacc[4] = fmaf(h1.x, at, aacc[4]); aacc[5] = fmaf(h1.y, at, aacc[5]);
    aacc[6] = fmaf(h1.z, at, aacc[6]); aacc[7] = fmaf(h1.w, at, aacc[7]);
  }
  for (int d = 0; d < 32; ++d) {
    float vt = v2[d * CC + c];
    float4 h0 = *(const float4*)&hs[128 + d][0];
    float4 h1 = *(const float4*)&hs[128 + d][4];
    vacc[0] = fmaf(h0.x, vt, vacc[0]); vacc[1] = fmaf(h0.y, vt, vacc[1]);
    vacc[2] = fmaf(h0.z, vt, vacc[2]); vacc[3] = fmaf(h0.w, vt, vacc[3]);
    vacc[4] = fmaf(h1.x, vt, vacc[4]); vacc[5] = fmaf(h1.y, vt, vacc[5]);
    vacc[6] = fmaf(h1.z, vt, vacc[6]); vacc[7] = fmaf(h1.w, vt, vacc[7]);
  }
  for (int d = 0; d < 128; ++d) {
    float gt = g2[d * CC + c];
    float4 h0 = *(const float4*)&hs[160 + d][0];
    float4 h1 = *(const float4*)&hs[160 + d][4];
    gacc[0] = fmaf(h0.x, gt, gacc[0]); gacc[1] = fmaf(h0.y, gt, gacc[1]);
    gacc[2] = fmaf(h0.z, gt, gacc[2]); gacc[3] = fmaf(h0.w, gt, gacc[3]);
    gacc[4] = fmaf(h1.x, gt, gacc[4]); gacc[5] = fmaf(h1.y, gt, gacc[5]);
    gacc[6] = fmaf(h1.z, gt, gacc[6]); gacc[7] = fmaf(h1.w, gt, gacc[7]);
  }
  float w0v = w0[c], a0v = a0[c], v0v = v0[c], kkv = kkc[c], kav = kac[c];
  float rkc = rk[c];
  for (int q = 0; q < 8; ++q) {
    int idx = (t0 + q) * CC + c;
    float kv = kbuf[idx], vv = vbuf[idx], vf = vfirst[idx];
    float d_ = 0.60653065971f * sigf(w0v + wacc[q]);   // sigmoid * e^-0.5
    float as = sigf(a0v + aacc[q]);
    float vs = sigf(v0v + vacc[q]);
    float vm = vv + (vf - vv) * vs;
    float kfv = kv * (1.0f + kav * (as - 1.0f));
    float kku = kv * kkv;
    float s = kku * kku;     // per-head L2 over 64 lanes (wave == head)
    s += __shfl_xor(s, 1);  s += __shfl_xor(s, 2);  s += __shfl_xor(s, 4);
    s += __shfl_xor(s, 8);  s += __shfl_xor(s, 16); s += __shfl_xor(s, 32);
    float nrm = fmaxf(sqrtf(s), 1e-12f);
    float kkn = kku / nrm;
    // per-head bonus: sum_c r*k_final*r_k  (wave == head)
    float bon = rbuf[idx] * kfv * rkc;
    bon += __shfl_xor(bon, 1);  bon += __shfl_xor(bon, 2);
    bon += __shfl_xor(bon, 4);  bon += __shfl_xor(bon, 8);
    bon += __shfl_xor(bon, 16); bon += __shfl_xor(bon, 32);
    if ((tid & 63) == 0) bonb[(t0 + q) * HH + (c >> 6)] = bon;
    dec[idx] = d_;
    aw[idx]  = -kkn; bw[idx] = kkn * as;
    kbuf[idx] = kfv; vbuf[idx] = vm; gval[idx] = gacc[q];
  }
}

// ---------------------------------------------------------------------------
// K7: WKV7 scan, ROW-split, barrier-free, 4-DEEP explicit prefetch ring.
// Grid = 512 blocks x 64 thr; block = one wave = (bh, row-group of 8).
// lane L: row = rg*8+(L>>3), cols = (L&7)*8..+8. sa/y via shfl_xor(1,2,4).
// Ring buf[4][10]+vvs[4] (~195 VGPRs) keeps loads live 4 steps; the
// asm memory fence after each step+reload pins issue order so the compiler
// cannot sink the prefetch to just-before-use (round-7 lesson: VGPR=64
// proved it had collapsed the ping-pong pipeline).
// ---------------------------------------------------------------------------
__global__ __launch_bounds__(64) void k_scan(
    const float* __restrict__ rbuf, const float* __restrict__ kf,
    const float* __restrict__ dec, const float* __restrict__ aw,
    const float* __restrict__ bw, const float* __restrict__ vbuf,
    const float* __restrict__ st0, float* __restrict__ ybuf) {
  int blk = blockIdx.x;                // 0..511
  int bh = blk >> 3, rg = blk & 7;
  int b = bh >> 5, h = bh & 31;
  int lane = threadIdx.x;
  int row = rg * 8 + (lane >> 3);
  int c0  = (lane & 7) * 8;
  size_t tokbase = (size_t)b * TT * CC + h * 64;

  float S[8];
  {
    const float* sp = st0 + ((size_t)bh * 64 + row) * 64 + c0;
#pragma unroll
    for (int i = 0; i < 8; ++i) S[i] = sp[i];
  }

  bool writer = ((lane & 7) == 0);
  float* yout = ybuf + tokbase + row;

  // ring: [slot][0..1]=r  [2..3]=k  [4..5]=d  [6..7]=a  [8..9]=b
  float4 buf[4][10];
  float  vvs[4];

#define LOADT(SL, T)                                                     \
  { size_t o = tokbase + (size_t)(T) * CC;                               \
    const float* pc = rbuf + o + c0;                                     \
    buf[SL][0] = *(const float4*)pc; buf[SL][1] = *(const float4*)(pc + 4); \
    pc = kf + o + c0;                                                    \
    buf[SL][2] = *(const float4*)pc; buf[SL][3] = *(const float4*)(pc + 4); \
    pc = dec + o + c0;                                                   \
    buf[SL][4] = *(const float4*)pc; buf[SL][5] = *(const float4*)(pc + 4); \
    pc = aw + o + c0;                                                    \
    buf[SL][6] = *(const float4*)pc; buf[SL][7] = *(const float4*)(pc + 4); \
    pc = bw + o + c0;                                                    \
    buf[SL][8] = *(const float4*)pc; buf[SL][9] = *(const float4*)(pc + 4); \
    vvs[SL] = vbuf[o + row]; }

  auto stepf = [&](int T, const float4* sb, float vvv) {
    float sa = fmaf(S[0], sb[6].x, fmaf(S[1], sb[6].y, fmaf(S[2], sb[6].z, S[3] * sb[6].w)))
             + fmaf(S[4], sb[7].x, fmaf(S[5], sb[7].y, fmaf(S[6], sb[7].z, S[7] * sb[7].w)));
    sa += __shfl_xor(sa, 1); sa += __shfl_xor(sa, 2); sa += __shfl_xor(sa, 4);
    float dc[8] = {sb[4].x, sb[4].y, sb[4].z, sb[4].w, sb[5].x, sb[5].y, sb[5].z, sb[5].w};
    float bc[8] = {sb[8].x, sb[8].y, sb[8].z, sb[8].w, sb[9].x, sb[9].y, sb[9].z, sb[9].w};
    float kc[8] = {sb[2].x, sb[2].y, sb[2].z, sb[2].w, sb[3].x, sb[3].y, sb[3].z, sb[3].w};
    float rc[8] = {sb[0].x, sb[0].y, sb[0].z, sb[0].w, sb[1].x, sb[1].y, sb[1].z, sb[1].w};
    float y = 0.f;
#pragma unroll
    for (int i = 0; i < 8; ++i) {
      float s = fmaf(S[i], dc[i], fmaf(sa, bc[i], vvv * kc[i]));
      S[i] = s;
      y = fmaf(s, rc[i], y);
    }
    y += __shfl_xor(y, 1); y += __shfl_xor(y, 2); y += __shfl_xor(y, 4);
    if (writer) yout[(size_t)T * CC] = y;
  };

#pragma unroll
  for (int i = 0; i < 4; ++i) LOADT(i, i);
  for (int t = 0; t < TT; t += 4) {
#pragma unroll
    for (int i = 0; i < 4; ++i) {
      stepf(t + i, buf[i], vvs[i]);
      int tn = t + 4 + i;
      if (tn < TT) LOADT(i, tn);
      asm volatile("" ::: "memory");   // pin: reload issues here, 4 steps early
    }
  }
#undef LOADT
}

// ---------------------------------------------------------------------------
// K8: post-scan epilogue: GroupNorm + bonus + g-gate, fully parallel.
// Block 256 = 4 waves; wave = one (token, head).
// ---------------------------------------------------------------------------
__global__ __launch_bounds__(256) void k_post(
    const float* __restrict__ ybuf, const float* __restrict__ vb,
    const float* __restrict__ gvb, const float* __restrict__ bonb,
    const float* __restrict__ gnw, const float* __restrict__ gnb,
    __hip_bfloat16* __restrict__ xoh, __hip_bfloat16* __restrict__ xol) {
  int tid = threadIdx.x, wv = tid >> 6, lane = tid & 63;
  int id = blockIdx.x * 4 + wv;        // 0..BT*HH-1
  int bt = id >> 5, h = id & 31;
  size_t base = (size_t)bt * CC + h * 64 + lane;
  float y = ybuf[base];
  float s1 = y, s2 = y * y;
#pragma unroll
  for (int off = 1; off < 64; off <<= 1) {
    s1 += __shfl_xor(s1, off);
    s2 += __shfl_xor(s2, off);
  }
  float mean = s1 * (1.0f / 64.0f);
  float var  = s2 * (1.0f / 64.0f) - mean * mean;
  float inv  = rsqrtf(var + GN_EPS);
  float x = fmaf((y - mean) * inv, gnw[h * 64 + lane], gnb[h * 64 + lane])
          + bonb[bt * HH + h] * vb[base];
  split_bf16(x * gvb[base], xoh[base], xol[base]);
}

// ---------------------------------------------------------------------------
extern "C" void kernel_launch(void* const* d_in, const int* in_sizes, int n_in,
                              void* d_out, int out_size, void* d_ws, size_t ws_size,
                              hipStream_t stream) {
  (void)in_sizes; (void)n_in; (void)out_size; (void)ws_size;
  const float* hid    = (const float*)d_in[0];
  const float* shift  = (const float*)d_in[1];
  const float* st0    = (const float*)d_in[2];
  const float* vfirst = (const float*)d_in[3];
  const float* xrc = (const float*)d_in[4];
  const float* xwc = (const float*)d_in[5];
  const float* xkc = (const float*)d_in[6];
  const float* xvc = (const float*)d_in[7];
  const float* xac = (const float*)d_in[8];
  const float* xgc = (const float*)d_in[9];
  const float* w0  = (const float*)d_in[10];
  const float* w1  = (const float*)d_in[11];
  const float* w2  = (const float*)d_in[12];
  const float* a0  = (const float*)d_in[13];
  const float* a1  = (const float*)d_in[14];
  const float* a2  = (const float*)d_in[15];
  const float* v0  = (const float*)d_in[16];
  const float* v1  = (const float*)d_in[17];
  const float* v2  = (const float*)d_in[18];
  const float* g1  = (const float*)d_in[19];
  const float* g2  = (const float*)d_in[20];
  const float* kkc = (const float*)d_in[21];
  const float* kac = (const float*)d_in[22];
  const float* rk  = (const float*)d_in[23];
  const float* Wr  = (const float*)d_in[24];
  const float* Wk  = (const float*)d_in[25];
  const float* Wv  = (const float*)d_in[26];
  const float* Wo  = (const float*)d_in[27];
  const float* gnw = (const float*)d_in[28];
  const float* gnb = (const float*)d_in[29];
  float* out = (float*)d_out;

  char* p = (char*)d_ws;
  auto alloc = [&](size_t n) { char* q = p; p += (n + 255) & ~(size_t)255; return q; };
  const size_t EL = (size_t)BT * CC;

  // --- alias pool (96 MiB): xrh..xvl + Wrh,Wrl dead by k_prep2 time;
  //     db/awb/bwb/gvb (64 MiB) overlay them.
  char* pool = p;
  __hip_bfloat16* xrh = (__hip_bfloat16*)alloc(EL * 2);
  __hip_bfloat16* xrl = (__hip_bfloat16*)alloc(EL * 2);
  __hip_bfloat16* xkh = (__hip_bfloat16*)alloc(EL * 2);
  __hip_bfloat16* xkl = (__hip_bfloat16*)alloc(EL * 2);
  __hip_bfloat16* xvh = (__hip_bfloat16*)alloc(EL * 2);
  __hip_bfloat16* xvl = (__hip_bfloat16*)alloc(EL * 2);
  __hip_bfloat16* Wrh = (__hip_bfloat16*)alloc((size_t)CC * CC * 2);
  __hip_bfloat16* Wrl = (__hip_bfloat16*)alloc((size_t)CC * CC * 2);
  float* db  = (float*)pool;           // overlays xrh+xrl
  float* awb = db + EL;                // overlays xkh+xkl
  float* bwb = db + 2 * EL;            // overlays xvh+xvl
  float* gvb = db + 3 * EL;            // overlays Wrh+Wrl

  __hip_bfloat16* Wkh = (__hip_bfloat16*)alloc((size_t)CC * CC * 2);
  __hip_bfloat16* Wkl = (__hip_bfloat16*)alloc((size_t)CC * CC * 2);
  float* ybuf = (float*)Wkh;           // overlays Wkh+Wkl (dead after k-GEMM)

  __hip_bfloat16* Wvh = (__hip_bfloat16*)alloc((size_t)CC * CC * 2);
  __hip_bfloat16* Wvl = (__hip_bfloat16*)alloc((size_t)CC * CC * 2);
  __hip_bfloat16* Woh = (__hip_bfloat16*)alloc((size_t)CC * CC * 2);
  __hip_bfloat16* Wol = (__hip_bfloat16*)alloc((size_t)CC * CC * 2);
  __hip_bfloat16* xw  = (__hip_bfloat16*)alloc(EL * 2);
  __hip_bfloat16* xa  = (__hip_bfloat16*)alloc(EL * 2);
  __hip_bfloat16* xg  = (__hip_bfloat16*)alloc(EL * 2);
  __hip_bfloat16* w1t = (__hip_bfloat16*)alloc((size_t)64  * CC * 2);
  __hip_bfloat16* a1t = (__hip_bfloat16*)alloc((size_t)64  * CC * 2);
  __hip_bfloat16* v1t = (__hip_bfloat16*)alloc((size_t)64  * CC * 2);
  __hip_bfloat16* g1t = (__hip_bfloat16*)alloc((size_t)128 * CC * 2);
  float* rb  = (float*)alloc(EL * 4);
  float* kb  = (float*)alloc(EL * 4);  // raw k, then k_final in place
  float* vb  = (float*)alloc(EL * 4);  // raw v, then v_mix in place
  float* h1w = (float*)alloc((size_t)BT * 64  * 4);
  float* h1a = (float*)alloc((size_t)BT * 64  * 4);
  float* h1v = (float*)alloc((size_t)BT * 64  * 4);
  float* h1g = (float*)alloc((size_t)BT * 128 * 4);
  __hip_bfloat16* xoh = (__hip_bfloat16*)alloc(EL * 2);
  __hip_bfloat16* xol = (__hip_bfloat16*)alloc(EL * 2);
  float* bonb = (float*)alloc((size_t)BT * HH * 4);   // per-(token,head) bonus
  // total ~204.5 MiB (fits: 220 MiB known-OK, 268 MiB crashed)

  k_prepx<<<16384, 256, 0, stream>>>(hid, shift, xrc, xwc, xkc, xvc, xac, xgc,
                                     xrh, xrl, xw, xkh, xkl, xvh, xvl, xa, xg);
  k_cvt2<<<16384, 256, 0, stream>>>(Wr, Wrh, Wrl);
  k_cvt2<<<16384, 256, 0, stream>>>(Wk, Wkh, Wkl);
  k_cvt2<<<16384, 256, 0, stream>>>(Wv, Wvh, Wvl);
  k_cvt2<<<16384, 256, 0, stream>>>(Wo, Woh, Wol);
  k_tr<<<512, 256, 0, stream>>>(w1, w1t, 64);
  k_tr<<<512, 256, 0, stream>>>(a1, a1t, 64);
  k_tr<<<512, 256, 0, stream>>>(v1, v1t, 32);
  k_tr<<<1024, 256, 0, stream>>>(g1, g1t, 128);

  k_gemm_bt3<<<dim3(16, 32), 256, 0, stream>>>(xrh, xrl, Wrh, Wrl, rb, BT, CC, CC);
  k_gemm_bt3<<<dim3(16, 32), 256, 0, stream>>>(xkh, xkl, Wkh, Wkl, kb, BT, CC, CC);
  k_gemm_bt3<<<dim3(16, 32), 256, 0, stream>>>(xvh, xvl, Wvh, Wvl, vb, BT, CC, CC);
  k_gemm_bt<<<dim3(16, 1),  256, 0, stream>>>(xw,  w1t, h1w, BT, 64, CC);
  k_gemm_bt<<<dim3(16, 1),  256, 0, stream>>>(xa,  a1t, h1a, BT, 64, CC);
  k_gemm_bt<<<dim3(16, 1),  256, 0, stream>>>(xvh, v1t, h1v, BT, 64, CC);
  k_gemm_bt<<<dim3(16, 2),  256, 0, stream>>>(xg,  g1t, h1g, BT, 128, CC);

  k_act<<<1024, 256, 0, stream>>>(h1w, h1g);
  // from here: xrh..xvl / Wrh,Wrl dead (db/awb/bwb/gvb overlay);
  //            Wkh/Wkl dead (ybuf overlay)
  k_prep2<<<dim3(8, 256), 256, 0, stream>>>(h1w, h1a, h1v, h1g, w2, a2, v2, g2,
                                            w0, a0, v0, kkc, kac, kb, vb, vfirst,
                                            rb, rk, db, awb, bwb, gvb, bonb);
  k_scan<<<512, 64, 0, stream>>>(rb, kb, db, awb, bwb, vb, st0, ybuf);
  k_post<<<16384, 256, 0, stream>>>(ybuf, vb, gvb, bonb, gnw, gnb, xoh, xol);
  k_gemm_bt3<<<dim3(16, 32), 256, 0, stream>>>(xoh, xol, Woh, Wol, out, BT, CC, CC);
}